// Round 1
// baseline (760.894 us; speedup 1.0000x reference)
//
#include <hip/hip_runtime.h>
#include <cstdint>
#include <cstddef>

#define IN_F 512
#define C1 64      // H1*F1
#define NH 8
#define FD 8
#define C2 40
#define NEG 0.2f

// ---------------- CSR build ----------------
__global__ __launch_bounds__(256) void hist_k(const int* __restrict__ dst, int* __restrict__ deg, int E) {
    int e = blockIdx.x * 256 + threadIdx.x;
    if (e < E) atomicAdd(&deg[dst[e]], 1);
}

__global__ __launch_bounds__(1024) void scan_local_k(const int* __restrict__ deg, int* __restrict__ rowp,
                                                     int* __restrict__ bsums, int n) {
    __shared__ int tmp[1024];
    int tx = threadIdx.x;
    int i = blockIdx.x * 1024 + tx;
    int v = (i < n) ? deg[i] : 0;
    tmp[tx] = v;
    __syncthreads();
    for (int d = 1; d < 1024; d <<= 1) {
        int t = (tx >= d) ? tmp[tx - d] : 0;
        __syncthreads();
        tmp[tx] += t;
        __syncthreads();
    }
    if (i < n) rowp[i] = tmp[tx] - v;   // exclusive within block
    if (tx == 1023) bsums[blockIdx.x] = tmp[tx];
}

__global__ __launch_bounds__(128) void scan_sums_k(int* bsums, int nb) {
    __shared__ int tmp[128];
    int tx = threadIdx.x;
    int v = (tx < nb) ? bsums[tx] : 0;
    tmp[tx] = v;
    __syncthreads();
    for (int d = 1; d < 128; d <<= 1) {
        int t = (tx >= d) ? tmp[tx - d] : 0;
        __syncthreads();
        tmp[tx] += t;
        __syncthreads();
    }
    if (tx < nb) bsums[tx] = tmp[tx] - v;  // exclusive
}

__global__ __launch_bounds__(1024) void scan_add_k(int* rowp, const int* __restrict__ bsums, int n) {
    int i = blockIdx.x * 1024 + threadIdx.x;
    if (i < n) rowp[i] += bsums[blockIdx.x];
}

__global__ __launch_bounds__(256) void scatter_k(const int* __restrict__ src, const int* __restrict__ dst,
                                                 const int* __restrict__ rowp, int* __restrict__ fill,
                                                 int* __restrict__ csr_src, int E) {
    int e = blockIdx.x * 256 + threadIdx.x;
    if (e >= E) return;
    int d = dst[e];
    int p = atomicAdd(&fill[d], 1);
    csr_src[rowp[d] + p] = src[e];
}

// ---------------- GEMM1: h1pre[N,64] = x[N,512] @ W1[512,64] ----------------
__global__ __launch_bounds__(256) void gemm1_k(const float* __restrict__ x, const float* __restrict__ W,
                                               float* __restrict__ h, int N) {
    __shared__ float As[16][64 + 4];  // [k][m]
    __shared__ float Bs[16][64];      // [k][n]
    int tid = threadIdx.x;
    int row0 = blockIdx.x * 64;
    int tx = tid & 15;   // col group
    int ty = tid >> 4;   // row group
    float acc[4][4] = {{0.f}};
    int lm = tid >> 2;         // 0..63: A row
    int lk4 = (tid & 3) * 4;   // A k quad
    int lk = tid >> 4;         // 0..15: B k
    int lc4 = (tid & 15) * 4;  // B col quad
    for (int k0 = 0; k0 < IN_F; k0 += 16) {
        float4 av = make_float4(0.f, 0.f, 0.f, 0.f);
        int n = row0 + lm;
        if (n < N) av = *(const float4*)(x + (size_t)n * IN_F + k0 + lk4);
        As[lk4 + 0][lm] = av.x;
        As[lk4 + 1][lm] = av.y;
        As[lk4 + 2][lm] = av.z;
        As[lk4 + 3][lm] = av.w;
        float4 bv = *(const float4*)(W + (size_t)(k0 + lk) * C1 + lc4);
        *(float4*)&Bs[lk][lc4] = bv;
        __syncthreads();
#pragma unroll
        for (int kk = 0; kk < 16; kk++) {
            float a[4], b[4];
#pragma unroll
            for (int i = 0; i < 4; i++) a[i] = As[kk][ty * 4 + i];
#pragma unroll
            for (int j = 0; j < 4; j++) b[j] = Bs[kk][tx * 4 + j];
#pragma unroll
            for (int i = 0; i < 4; i++)
#pragma unroll
                for (int j = 0; j < 4; j++) acc[i][j] += a[i] * b[j];
        }
        __syncthreads();
    }
#pragma unroll
    for (int i = 0; i < 4; i++) {
        int n = row0 + ty * 4 + i;
        if (n < N) {
            float4 v = make_float4(acc[i][0], acc[i][1], acc[i][2], acc[i][3]);
            *(float4*)(h + (size_t)n * C1 + tx * 4) = v;
        }
    }
}

// ---------------- attn coefs layer1: el/er[N,8] ----------------
__global__ __launch_bounds__(256) void attn1_k(const float* __restrict__ h, const float* __restrict__ al,
                                               const float* __restrict__ ar, float* __restrict__ el,
                                               float* __restrict__ er, int N) {
    int idx = blockIdx.x * 256 + threadIdx.x;
    if (idx >= N * NH) return;
    int n = idx >> 3, hd = idx & 7;
    const float4* hp = (const float4*)(h + (size_t)n * C1 + hd * FD);
    const float4* alp = (const float4*)(al + hd * FD);
    const float4* arp = (const float4*)(ar + hd * FD);
    float4 v0 = hp[0], v1 = hp[1];
    float4 a0 = alp[0], a1 = alp[1];
    float4 r0 = arp[0], r1 = arp[1];
    float e_l = v0.x * a0.x + v0.y * a0.y + v0.z * a0.z + v0.w * a0.w +
                v1.x * a1.x + v1.y * a1.y + v1.z * a1.z + v1.w * a1.w;
    float e_r = v0.x * r0.x + v0.y * r0.y + v0.z * r0.z + v0.w * r0.w +
                v1.x * r1.x + v1.y * r1.y + v1.z * r1.z + v1.w * r1.w;
    el[idx] = e_l;
    er[idx] = e_r;
}

// ---------------- layer1 fused edge-softmax + aggregate + bias + elu ----------------
// thread = (node, head)
__global__ __launch_bounds__(256) void l1_fused_k(const float* __restrict__ h, const float* __restrict__ el,
                                                  const float* __restrict__ er, const int* __restrict__ rowp,
                                                  const int* __restrict__ deg, const int* __restrict__ csr_src,
                                                  const float* __restrict__ b1, float* __restrict__ hout, int N) {
    int idx = blockIdx.x * 256 + threadIdx.x;
    if (idx >= N * NH) return;
    int n = idx >> 3, hd = idx & 7;
    int start = rowp[n], cnt = deg[n];
    float erd = er[idx];
    // pass 1: softmax denominator (no max-shift needed; |e| small)
    float s = 0.f;
    for (int i = 0; i < cnt; i++) {
        int sn = csr_src[start + i];
        float e = el[sn * NH + hd] + erd;
        e = e > 0.f ? e : NEG * e;
        s += __expf(e);
    }
    float sinv = (cnt > 0) ? 1.f / s : 0.f;
    // pass 2: aggregate
    float4 acc0 = make_float4(0.f, 0.f, 0.f, 0.f);
    float4 acc1 = make_float4(0.f, 0.f, 0.f, 0.f);
    for (int i = 0; i < cnt; i++) {
        int sn = csr_src[start + i];
        float e = el[sn * NH + hd] + erd;
        e = e > 0.f ? e : NEG * e;
        float a = __expf(e) * sinv;
        const float4* hp = (const float4*)(h + (size_t)sn * C1 + hd * FD);
        float4 v0 = hp[0], v1 = hp[1];
        acc0.x += a * v0.x; acc0.y += a * v0.y; acc0.z += a * v0.z; acc0.w += a * v0.w;
        acc1.x += a * v1.x; acc1.y += a * v1.y; acc1.z += a * v1.z; acc1.w += a * v1.w;
    }
    const float4* bp = (const float4*)(b1 + hd * FD);
    float4 bb0 = bp[0], bb1 = bp[1];
    float o[8] = {acc0.x + bb0.x, acc0.y + bb0.y, acc0.z + bb0.z, acc0.w + bb0.w,
                  acc1.x + bb1.x, acc1.y + bb1.y, acc1.z + bb1.z, acc1.w + bb1.w};
#pragma unroll
    for (int f = 0; f < 8; f++) o[f] = o[f] > 0.f ? o[f] : (__expf(o[f]) - 1.f);  // elu
    float4* op = (float4*)(hout + (size_t)n * C1 + hd * FD);
    op[0] = make_float4(o[0], o[1], o[2], o[3]);
    op[1] = make_float4(o[4], o[5], o[6], o[7]);
}

// ---------------- GEMM2: h2pre[N,40] = h1[N,64] @ W2[64,40] ----------------
__global__ __launch_bounds__(256) void gemm2_k(const float* __restrict__ h1, const float* __restrict__ W2,
                                               float* __restrict__ h2, int N) {
    __shared__ float hs[32 * C1];
    __shared__ float ws[C1 * C2];
    int t = threadIdx.x;
    int n0 = blockIdx.x * 32;
    for (int i = t; i < C1 * C2; i += 256) ws[i] = W2[i];
    for (int i = t; i < 32 * C1; i += 256) {
        int r = i >> 6, c = i & 63;
        int n = n0 + r;
        hs[i] = (n < N) ? h1[(size_t)n * C1 + c] : 0.f;
    }
    __syncthreads();
    for (int o = t; o < 32 * C2; o += 256) {
        int r = o / C2, c = o % C2;
        int n = n0 + r;
        if (n < N) {
            float s = 0.f;
#pragma unroll
            for (int k = 0; k < C1; k++) s += hs[r * C1 + k] * ws[k * C2 + c];
            h2[(size_t)n * C2 + c] = s;
        }
    }
}

// ---------------- attn coefs layer2: el2/er2[N] ----------------
__global__ __launch_bounds__(256) void attn2_k(const float* __restrict__ h2, const float* __restrict__ al,
                                               const float* __restrict__ ar, float* __restrict__ el,
                                               float* __restrict__ er, int N) {
    int n = blockIdx.x * 256 + threadIdx.x;
    if (n >= N) return;
    const float4* hp = (const float4*)(h2 + (size_t)n * C2);
    float e_l = 0.f, e_r = 0.f;
#pragma unroll
    for (int q = 0; q < C2 / 4; q++) {
        float4 v = hp[q];
        const float4 a = ((const float4*)al)[q];
        const float4 r = ((const float4*)ar)[q];
        e_l += v.x * a.x + v.y * a.y + v.z * a.z + v.w * a.w;
        e_r += v.x * r.x + v.y * r.y + v.z * r.z + v.w * r.w;
    }
    el[n] = e_l;
    er[n] = e_r;
}

// ---------------- layer2 fused: softmax + aggregate + bias + log_softmax ----------------
// thread = node
__global__ __launch_bounds__(256) void l2_fused_k(const float* __restrict__ h2, const float* __restrict__ el,
                                                  const float* __restrict__ er, const int* __restrict__ rowp,
                                                  const int* __restrict__ deg, const int* __restrict__ csr_src,
                                                  const float* __restrict__ b2, float* __restrict__ out, int N) {
    int n = blockIdx.x * 256 + threadIdx.x;
    if (n >= N) return;
    int start = rowp[n], cnt = deg[n];
    float erd = er[n];
    float s = 0.f;
    for (int i = 0; i < cnt; i++) {
        int sn = csr_src[start + i];
        float e = el[sn] + erd;
        e = e > 0.f ? e : NEG * e;
        s += __expf(e);
    }
    float sinv = (cnt > 0) ? 1.f / s : 0.f;
    float acc[C2];
#pragma unroll
    for (int j = 0; j < C2; j++) acc[j] = 0.f;
    for (int i = 0; i < cnt; i++) {
        int sn = csr_src[start + i];
        float e = el[sn] + erd;
        e = e > 0.f ? e : NEG * e;
        float a = __expf(e) * sinv;
        const float4* hp = (const float4*)(h2 + (size_t)sn * C2);
#pragma unroll
        for (int q = 0; q < C2 / 4; q++) {
            float4 v = hp[q];
            acc[q * 4 + 0] += a * v.x;
            acc[q * 4 + 1] += a * v.y;
            acc[q * 4 + 2] += a * v.z;
            acc[q * 4 + 3] += a * v.w;
        }
    }
#pragma unroll
    for (int j = 0; j < C2; j++) acc[j] += b2[j];
    // log_softmax over 40
    float m = acc[0];
#pragma unroll
    for (int j = 1; j < C2; j++) m = fmaxf(m, acc[j]);
    float se = 0.f;
#pragma unroll
    for (int j = 0; j < C2; j++) se += __expf(acc[j] - m);
    float ls = __logf(se) + m;
    float* op = out + (size_t)n * C2;
#pragma unroll
    for (int j = 0; j < C2; j++) op[j] = acc[j] - ls;
}

extern "C" void kernel_launch(void* const* d_in, const int* in_sizes, int n_in,
                              void* d_out, int out_size, void* d_ws, size_t ws_size,
                              hipStream_t stream) {
    (void)n_in; (void)out_size; (void)ws_size;
    const float* x   = (const float*)d_in[0];
    const int*   src = (const int*)d_in[1];
    const int*   dst = (const int*)d_in[2];
    const float* W1  = (const float*)d_in[3];
    const float* al1 = (const float*)d_in[4];
    const float* ar1 = (const float*)d_in[5];
    const float* b1  = (const float*)d_in[6];
    const float* W2  = (const float*)d_in[7];
    const float* al2 = (const float*)d_in[8];
    const float* ar2 = (const float*)d_in[9];
    const float* b2  = (const float*)d_in[10];
    float* out = (float*)d_out;
    const int N = in_sizes[0] / IN_F;
    const int E = in_sizes[1];

    char* w = (char*)d_ws;
    auto alloc = [&](size_t bytes) -> char* {
        char* p = w;
        w += (bytes + 255) & ~(size_t)255;
        return p;
    };
    int* deg     = (int*)alloc((size_t)N * 4);
    int* fill    = (int*)alloc((size_t)N * 4);
    int* rowp    = (int*)alloc((size_t)N * 4);
    int* bsums   = (int*)alloc(512);
    int* csr_src = (int*)alloc((size_t)E * 4);
    float* h1pre = (float*)alloc((size_t)N * C1 * 4);
    float* el1   = (float*)alloc((size_t)N * NH * 4);
    float* er1   = (float*)alloc((size_t)N * NH * 4);
    float* h1    = (float*)alloc((size_t)N * C1 * 4);
    float* h2pre = (float*)alloc((size_t)N * C2 * 4);
    float* el2   = (float*)alloc((size_t)N * 4);
    float* er2   = (float*)alloc((size_t)N * 4);

    hipMemsetAsync(deg, 0, (size_t)N * 4, stream);
    hipMemsetAsync(fill, 0, (size_t)N * 4, stream);

    int ebl = (E + 255) / 256;
    int nb = (N + 1023) / 1024;
    hist_k<<<ebl, 256, 0, stream>>>(dst, deg, E);
    scan_local_k<<<nb, 1024, 0, stream>>>(deg, rowp, bsums, N);
    scan_sums_k<<<1, 128, 0, stream>>>(bsums, nb);
    scan_add_k<<<nb, 1024, 0, stream>>>(rowp, bsums, N);
    scatter_k<<<ebl, 256, 0, stream>>>(src, dst, rowp, fill, csr_src, E);

    gemm1_k<<<(N + 63) / 64, 256, 0, stream>>>(x, W1, h1pre, N);
    attn1_k<<<(N * NH + 255) / 256, 256, 0, stream>>>(h1pre, al1, ar1, el1, er1, N);
    l1_fused_k<<<(N * NH + 255) / 256, 256, 0, stream>>>(h1pre, el1, er1, rowp, deg, csr_src, b1, h1, N);

    gemm2_k<<<(N + 31) / 32, 256, 0, stream>>>(h1, W2, h2pre, N);
    attn2_k<<<(N + 255) / 256, 256, 0, stream>>>(h2pre, al2, ar2, el2, er2, N);
    l2_fused_k<<<(N + 255) / 256, 256, 0, stream>>>(h2pre, el2, er2, rowp, deg, csr_src, b2, out, N);
}

// Round 2
// 745.725 us; speedup vs baseline: 1.0203x; 1.0203x over previous
//
#include <hip/hip_runtime.h>
#include <cstdint>
#include <cstddef>

#define IN_F 512
#define C1 64      // H1*F1
#define NH 8
#define FD 8
#define C2 40
#define NEG 0.2f

typedef __attribute__((ext_vector_type(8))) short bf16x8;
typedef __attribute__((ext_vector_type(4))) float f32x4;

__device__ inline unsigned short f32_to_bf16_rne(float f) {
    unsigned int u = __float_as_uint(f);
    unsigned int r = (u + 0x7FFFu + ((u >> 16) & 1u)) >> 16;
    return (unsigned short)r;
}
__device__ inline float bf16_to_f32(unsigned short s) {
    return __uint_as_float(((unsigned int)s) << 16);
}

// ---------------- CSR build ----------------
__global__ __launch_bounds__(256) void hist_k(const int* __restrict__ dst, int* __restrict__ deg, int E) {
    int e = blockIdx.x * 256 + threadIdx.x;
    if (e < E) atomicAdd(&deg[dst[e]], 1);
}

__global__ __launch_bounds__(1024) void scan_local_k(const int* __restrict__ deg, int* __restrict__ rowp,
                                                     int* __restrict__ bsums, int n) {
    __shared__ int tmp[1024];
    int tx = threadIdx.x;
    int i = blockIdx.x * 1024 + tx;
    int v = (i < n) ? deg[i] : 0;
    tmp[tx] = v;
    __syncthreads();
    for (int d = 1; d < 1024; d <<= 1) {
        int t = (tx >= d) ? tmp[tx - d] : 0;
        __syncthreads();
        tmp[tx] += t;
        __syncthreads();
    }
    if (i < n) rowp[i] = tmp[tx] - v;   // exclusive within block
    if (tx == 1023) bsums[blockIdx.x] = tmp[tx];
}

__global__ __launch_bounds__(128) void scan_sums_k(int* bsums, int nb) {
    __shared__ int tmp[128];
    int tx = threadIdx.x;
    int v = (tx < nb) ? bsums[tx] : 0;
    tmp[tx] = v;
    __syncthreads();
    for (int d = 1; d < 128; d <<= 1) {
        int t = (tx >= d) ? tmp[tx - d] : 0;
        __syncthreads();
        tmp[tx] += t;
        __syncthreads();
    }
    if (tx < nb) bsums[tx] = tmp[tx] - v;  // exclusive
}

__global__ __launch_bounds__(1024) void scan_add_k(int* rowp, const int* __restrict__ bsums, int n) {
    int i = blockIdx.x * 1024 + threadIdx.x;
    if (i < n) rowp[i] += bsums[blockIdx.x];
}

__global__ __launch_bounds__(256) void scatter_k(const int* __restrict__ src, const int* __restrict__ dst,
                                                 const int* __restrict__ rowp, int* __restrict__ fill,
                                                 int* __restrict__ csr_src, int E) {
    int e = blockIdx.x * 256 + threadIdx.x;
    if (e >= E) return;
    int d = dst[e];
    int p = atomicAdd(&fill[d], 1);
    csr_src[rowp[d] + p] = src[e];
}

// ---------------- W1 preconvert: Wt_hi/Wt_lo[col][k] split-bf16 ----------------
__global__ __launch_bounds__(256) void wt_pre_k(const float* __restrict__ W1,
                                                unsigned short* __restrict__ wt_hi,
                                                unsigned short* __restrict__ wt_lo) {
    int id = blockIdx.x * 256 + threadIdx.x;   // id over 512*64
    if (id >= IN_F * C1) return;
    int col = id & (C1 - 1);
    int k = id >> 6;
    float w = W1[id];
    unsigned short hb = f32_to_bf16_rne(w);
    unsigned short lb = f32_to_bf16_rne(w - bf16_to_f32(hb));
    wt_hi[(size_t)col * IN_F + k] = hb;
    wt_lo[(size_t)col * IN_F + k] = lb;
}

// ---------------- GEMM1 via split-bf16 MFMA: h1pre[N,64] = x[N,512] @ W1 ----------------
// block = 256 thr = 4 waves; block tile 64 rows x 64 cols; wave tile 16 rows x 64 cols.
// MFMA 16x16x32: A[m=lane&15][k=quad*8+j]; C/D: col=lane&15, row=quad*4+reg.
__global__ __launch_bounds__(256) void gemm1_mfma_k(const float* __restrict__ x,
                                                    const unsigned short* __restrict__ wt_hi,
                                                    const unsigned short* __restrict__ wt_lo,
                                                    float* __restrict__ h, int N) {
    int wave = threadIdx.x >> 6;
    int lane = threadIdx.x & 63;
    int m = lane & 15;
    int q = lane >> 4;
    int row = blockIdx.x * 64 + wave * 16 + m;
    bool valid = row < N;
    const float* xp = x + (size_t)row * IN_F + q * 8;
    f32x4 acc[4];
#pragma unroll
    for (int ct = 0; ct < 4; ct++) acc[ct] = (f32x4){0.f, 0.f, 0.f, 0.f};

    for (int k0 = 0; k0 < IN_F; k0 += 32) {
        bf16x8 a_hi = (bf16x8)(short)0;
        bf16x8 a_lo = (bf16x8)(short)0;
        if (valid) {
            float4 p0 = *(const float4*)(xp + k0);
            float4 p1 = *(const float4*)(xp + k0 + 4);
            float v[8] = {p0.x, p0.y, p0.z, p0.w, p1.x, p1.y, p1.z, p1.w};
#pragma unroll
            for (int j = 0; j < 8; j++) {
                unsigned short hb = f32_to_bf16_rne(v[j]);
                unsigned short lb = f32_to_bf16_rne(v[j] - bf16_to_f32(hb));
                a_hi[j] = (short)hb;
                a_lo[j] = (short)lb;
            }
        }
#pragma unroll
        for (int ct = 0; ct < 4; ct++) {
            int col = ct * 16 + m;
            const bf16x8 b_hi = *(const bf16x8*)(wt_hi + (size_t)col * IN_F + k0 + q * 8);
            const bf16x8 b_lo = *(const bf16x8*)(wt_lo + (size_t)col * IN_F + k0 + q * 8);
            acc[ct] = __builtin_amdgcn_mfma_f32_16x16x32_bf16(a_hi, b_hi, acc[ct], 0, 0, 0);
            acc[ct] = __builtin_amdgcn_mfma_f32_16x16x32_bf16(a_hi, b_lo, acc[ct], 0, 0, 0);
            acc[ct] = __builtin_amdgcn_mfma_f32_16x16x32_bf16(a_lo, b_hi, acc[ct], 0, 0, 0);
        }
    }
    int rbase = blockIdx.x * 64 + wave * 16 + q * 4;
#pragma unroll
    for (int r = 0; r < 4; r++) {
        int ro = rbase + r;
        if (ro < N) {
#pragma unroll
            for (int ct = 0; ct < 4; ct++)
                h[(size_t)ro * C1 + ct * 16 + m] = acc[ct][r];
        }
    }
}

// ---------------- attn coefs layer1: el/er[N,8] ----------------
__global__ __launch_bounds__(256) void attn1_k(const float* __restrict__ h, const float* __restrict__ al,
                                               const float* __restrict__ ar, float* __restrict__ el,
                                               float* __restrict__ er, int N) {
    int idx = blockIdx.x * 256 + threadIdx.x;
    if (idx >= N * NH) return;
    int n = idx >> 3, hd = idx & 7;
    const float4* hp = (const float4*)(h + (size_t)n * C1 + hd * FD);
    const float4* alp = (const float4*)(al + hd * FD);
    const float4* arp = (const float4*)(ar + hd * FD);
    float4 v0 = hp[0], v1 = hp[1];
    float4 a0 = alp[0], a1 = alp[1];
    float4 r0 = arp[0], r1 = arp[1];
    float e_l = v0.x * a0.x + v0.y * a0.y + v0.z * a0.z + v0.w * a0.w +
                v1.x * a1.x + v1.y * a1.y + v1.z * a1.z + v1.w * a1.w;
    float e_r = v0.x * r0.x + v0.y * r0.y + v0.z * r0.z + v0.w * r0.w +
                v1.x * r1.x + v1.y * r1.y + v1.z * r1.z + v1.w * r1.w;
    el[idx] = e_l;
    er[idx] = e_r;
}

// ---------------- layer1 fused: single-pass edge softmax-agg + bias + elu + GEMM2 + attn2 ----------------
// block = 256 thr = 32 nodes x 8 heads. h1 lives only in LDS.
__global__ __launch_bounds__(256) void l1_agg_k(const float* __restrict__ h,
                                                const float* __restrict__ el, const float* __restrict__ er,
                                                const int* __restrict__ rowp, const int* __restrict__ deg,
                                                const int* __restrict__ csr_src, const float* __restrict__ b1,
                                                const float* __restrict__ W2, const float* __restrict__ al2,
                                                const float* __restrict__ ar2,
                                                float* __restrict__ h2pre, float* __restrict__ el2o,
                                                float* __restrict__ er2o, int N) {
    __shared__ float ws[C1 * C2];       // W2: 64x40
    __shared__ float hs[32][C1];        // h1 tile
    __shared__ float h2s[32][C2];       // h2 tile
    __shared__ float a2s[2 * C2];
    int tid = threadIdx.x;
    for (int i = tid; i < C1 * C2; i += 256) ws[i] = W2[i];
    if (tid < C2) a2s[tid] = al2[tid];
    else if (tid < 2 * C2) a2s[tid] = ar2[tid - C2];

    int n0 = blockIdx.x * 32;
    int ln = tid >> 3;
    int hd = tid & 7;
    int n = n0 + ln;
    float4 acc0 = make_float4(0.f, 0.f, 0.f, 0.f);
    float4 acc1 = make_float4(0.f, 0.f, 0.f, 0.f);
    float s = 0.f;
    if (n < N) {
        int start = rowp[n], cnt = deg[n];
        float erd = er[n * NH + hd];
        for (int i = 0; i < cnt; i++) {
            int sn = csr_src[start + i];
            float e = el[sn * NH + hd] + erd;
            e = e > 0.f ? e : NEG * e;
            float w = __expf(e);
            s += w;
            const float4* hp = (const float4*)(h + (size_t)sn * C1 + hd * FD);
            float4 v0 = hp[0], v1 = hp[1];
            acc0.x += w * v0.x; acc0.y += w * v0.y; acc0.z += w * v0.z; acc0.w += w * v0.w;
            acc1.x += w * v1.x; acc1.y += w * v1.y; acc1.z += w * v1.z; acc1.w += w * v1.w;
        }
    }
    float sinv = (s > 0.f) ? 1.f / s : 0.f;
    const float4* bp = (const float4*)(b1 + hd * FD);
    float4 bb0 = bp[0], bb1 = bp[1];
    float o[8] = {acc0.x * sinv + bb0.x, acc0.y * sinv + bb0.y, acc0.z * sinv + bb0.z, acc0.w * sinv + bb0.w,
                  acc1.x * sinv + bb1.x, acc1.y * sinv + bb1.y, acc1.z * sinv + bb1.z, acc1.w * sinv + bb1.w};
#pragma unroll
    for (int f = 0; f < 8; f++) o[f] = o[f] > 0.f ? o[f] : (__expf(o[f]) - 1.f);  // elu
    *(float4*)&hs[ln][hd * FD] = make_float4(o[0], o[1], o[2], o[3]);
    *(float4*)&hs[ln][hd * FD + 4] = make_float4(o[4], o[5], o[6], o[7]);
    __syncthreads();

    // GEMM2 tile: h2s[32][40] = hs[32][64] @ ws[64][40]
    for (int oidx = tid; oidx < 32 * C2; oidx += 256) {
        int r = oidx / C2, c = oidx % C2;
        float sum = 0.f;
#pragma unroll
        for (int k = 0; k < C1; k++) sum += hs[r][k] * ws[k * C2 + c];
        h2s[r][c] = sum;
        int nn = n0 + r;
        if (nn < N) h2pre[(size_t)nn * C2 + c] = sum;
    }
    __syncthreads();

    // attn2 for this tile's nodes
    if (tid < 32) {
        int nn = n0 + tid;
        if (nn < N) {
            float e_l = 0.f, e_r = 0.f;
#pragma unroll
            for (int c = 0; c < C2; c++) {
                float v = h2s[tid][c];
                e_l += v * a2s[c];
                e_r += v * a2s[C2 + c];
            }
            el2o[nn] = e_l;
            er2o[nn] = e_r;
        }
    }
}

// ---------------- layer2 fused: single-pass softmax-agg + bias + log_softmax ----------------
__global__ __launch_bounds__(256) void l2_fused_k(const float* __restrict__ h2, const float* __restrict__ el,
                                                  const float* __restrict__ er, const int* __restrict__ rowp,
                                                  const int* __restrict__ deg, const int* __restrict__ csr_src,
                                                  const float* __restrict__ b2, float* __restrict__ out, int N) {
    int n = blockIdx.x * 256 + threadIdx.x;
    if (n >= N) return;
    int start = rowp[n], cnt = deg[n];
    float erd = er[n];
    float s = 0.f;
    float acc[C2];
#pragma unroll
    for (int j = 0; j < C2; j++) acc[j] = 0.f;
    for (int i = 0; i < cnt; i++) {
        int sn = csr_src[start + i];
        float e = el[sn] + erd;
        e = e > 0.f ? e : NEG * e;
        float a = __expf(e);
        s += a;
        const float4* hp = (const float4*)(h2 + (size_t)sn * C2);
#pragma unroll
        for (int qd = 0; qd < C2 / 4; qd++) {
            float4 v = hp[qd];
            acc[qd * 4 + 0] += a * v.x;
            acc[qd * 4 + 1] += a * v.y;
            acc[qd * 4 + 2] += a * v.z;
            acc[qd * 4 + 3] += a * v.w;
        }
    }
    float sinv = (s > 0.f) ? 1.f / s : 0.f;
#pragma unroll
    for (int j = 0; j < C2; j++) acc[j] = acc[j] * sinv + b2[j];
    // log_softmax over 40
    float m = acc[0];
#pragma unroll
    for (int j = 1; j < C2; j++) m = fmaxf(m, acc[j]);
    float se = 0.f;
#pragma unroll
    for (int j = 0; j < C2; j++) se += __expf(acc[j] - m);
    float ls = __logf(se) + m;
    float* op = out + (size_t)n * C2;
#pragma unroll
    for (int j = 0; j < C2; j++) op[j] = acc[j] - ls;
}

extern "C" void kernel_launch(void* const* d_in, const int* in_sizes, int n_in,
                              void* d_out, int out_size, void* d_ws, size_t ws_size,
                              hipStream_t stream) {
    (void)n_in; (void)out_size; (void)ws_size;
    const float* x   = (const float*)d_in[0];
    const int*   src = (const int*)d_in[1];
    const int*   dst = (const int*)d_in[2];
    const float* W1  = (const float*)d_in[3];
    const float* al1 = (const float*)d_in[4];
    const float* ar1 = (const float*)d_in[5];
    const float* b1  = (const float*)d_in[6];
    const float* W2  = (const float*)d_in[7];
    const float* al2 = (const float*)d_in[8];
    const float* ar2 = (const float*)d_in[9];
    const float* b2  = (const float*)d_in[10];
    float* out = (float*)d_out;
    const int N = in_sizes[0] / IN_F;
    const int E = in_sizes[1];

    char* w = (char*)d_ws;
    auto alloc = [&](size_t bytes) -> char* {
        char* p = w;
        w += (bytes + 255) & ~(size_t)255;
        return p;
    };
    int* deg     = (int*)alloc((size_t)N * 4);
    int* fill    = (int*)alloc((size_t)N * 4);
    int* rowp    = (int*)alloc((size_t)N * 4);
    int* bsums   = (int*)alloc(512);
    int* csr_src = (int*)alloc((size_t)E * 4);
    unsigned short* wt_hi = (unsigned short*)alloc((size_t)IN_F * C1 * 2);
    unsigned short* wt_lo = (unsigned short*)alloc((size_t)IN_F * C1 * 2);
    float* h1pre = (float*)alloc((size_t)N * C1 * 4);
    float* el1   = (float*)alloc((size_t)N * NH * 4);
    float* er1   = (float*)alloc((size_t)N * NH * 4);
    float* h2pre = (float*)alloc((size_t)N * C2 * 4);
    float* el2   = (float*)alloc((size_t)N * 4);
    float* er2   = (float*)alloc((size_t)N * 4);

    hipMemsetAsync(deg, 0, (size_t)N * 4, stream);
    hipMemsetAsync(fill, 0, (size_t)N * 4, stream);

    int ebl = (E + 255) / 256;
    int nb = (N + 1023) / 1024;
    hist_k<<<ebl, 256, 0, stream>>>(dst, deg, E);
    scan_local_k<<<nb, 1024, 0, stream>>>(deg, rowp, bsums, N);
    scan_sums_k<<<1, 128, 0, stream>>>(bsums, nb);
    scan_add_k<<<nb, 1024, 0, stream>>>(rowp, bsums, N);
    scatter_k<<<ebl, 256, 0, stream>>>(src, dst, rowp, fill, csr_src, E);

    wt_pre_k<<<(IN_F * C1 + 255) / 256, 256, 0, stream>>>(W1, wt_hi, wt_lo);
    gemm1_mfma_k<<<(N + 63) / 64, 256, 0, stream>>>(x, wt_hi, wt_lo, h1pre, N);
    attn1_k<<<(N * NH + 255) / 256, 256, 0, stream>>>(h1pre, al1, ar1, el1, er1, N);
    l1_agg_k<<<(N + 31) / 32, 256, 0, stream>>>(h1pre, el1, er1, rowp, deg, csr_src, b1,
                                                W2, al2, ar2, h2pre, el2, er2, N);
    l2_fused_k<<<(N + 255) / 256, 256, 0, stream>>>(h2pre, el2, er2, rowp, deg, csr_src, b2, out, N);
}

// Round 4
// 648.919 us; speedup vs baseline: 1.1726x; 1.1492x over previous
//
#include <hip/hip_runtime.h>
#include <cstdint>
#include <cstddef>

#define IN_F 512
#define C1 64      // H1*F1
#define NH 8
#define FD 8
#define C2 40
#define NEG 0.2f

typedef __attribute__((ext_vector_type(8))) short bf16x8;
typedef __attribute__((ext_vector_type(4))) float f32x4;

__device__ inline unsigned short f32_to_bf16_rne(float f) {
    unsigned int u = __float_as_uint(f);
    unsigned int r = (u + 0x7FFFu + ((u >> 16) & 1u)) >> 16;
    return (unsigned short)r;
}
__device__ inline float bf16_to_f32(unsigned short s) {
    return __uint_as_float(((unsigned int)s) << 16);
}

// ---------------- CSR build ----------------
__global__ __launch_bounds__(256) void hist_k(const int* __restrict__ dst, int* __restrict__ deg, int E) {
    int e = blockIdx.x * 256 + threadIdx.x;
    if (e < E) atomicAdd(&deg[dst[e]], 1);
}

__global__ __launch_bounds__(1024) void scan_local_k(const int* __restrict__ deg, int* __restrict__ rowp,
                                                     int* __restrict__ bsums, int n) {
    __shared__ int tmp[1024];
    int tx = threadIdx.x;
    int i = blockIdx.x * 1024 + tx;
    int v = (i < n) ? deg[i] : 0;
    tmp[tx] = v;
    __syncthreads();
    for (int d = 1; d < 1024; d <<= 1) {
        int t = (tx >= d) ? tmp[tx - d] : 0;
        __syncthreads();
        tmp[tx] += t;
        __syncthreads();
    }
    if (i < n) rowp[i] = tmp[tx] - v;   // exclusive within block
    if (tx == 1023) bsums[blockIdx.x] = tmp[tx];
}

__global__ __launch_bounds__(128) void scan_sums_k(int* bsums, int nb) {
    __shared__ int tmp[128];
    int tx = threadIdx.x;
    int v = (tx < nb) ? bsums[tx] : 0;
    tmp[tx] = v;
    __syncthreads();
    for (int d = 1; d < 128; d <<= 1) {
        int t = (tx >= d) ? tmp[tx - d] : 0;
        __syncthreads();
        tmp[tx] += t;
        __syncthreads();
    }
    if (tx < nb) bsums[tx] = tmp[tx] - v;  // exclusive
}

__global__ __launch_bounds__(1024) void scan_add_k(int* rowp, const int* __restrict__ bsums, int n) {
    int i = blockIdx.x * 1024 + threadIdx.x;
    if (i < n) rowp[i] += bsums[blockIdx.x];
}

__global__ __launch_bounds__(256) void scatter_k(const int* __restrict__ src, const int* __restrict__ dst,
                                                 const int* __restrict__ rowp, int* __restrict__ fill,
                                                 int* __restrict__ csr_src, int E) {
    int e = blockIdx.x * 256 + threadIdx.x;
    if (e >= E) return;
    int d = dst[e];
    int p = atomicAdd(&fill[d], 1);
    csr_src[rowp[d] + p] = src[e];
}

// ---------------- W1 preconvert: Wt_hi/Wt_lo[col][k] split-bf16 ----------------
__global__ __launch_bounds__(256) void wt_pre_k(const float* __restrict__ W1,
                                                unsigned short* __restrict__ wt_hi,
                                                unsigned short* __restrict__ wt_lo) {
    int id = blockIdx.x * 256 + threadIdx.x;   // id over 512*64
    if (id >= IN_F * C1) return;
    int col = id & (C1 - 1);
    int k = id >> 6;
    float w = W1[id];
    unsigned short hb = f32_to_bf16_rne(w);
    unsigned short lb = f32_to_bf16_rne(w - bf16_to_f32(hb));
    wt_hi[(size_t)col * IN_F + k] = hb;
    wt_lo[(size_t)col * IN_F + k] = lb;
}

// ---------------- GEMM1 via split-bf16 MFMA, W staged in LDS (async, dbuf), x reg-prefetch ----------------
// block 256 = 4 waves; block tile 64 rows x 64 cols; wave tile 16 rows x 64 cols.
// K chunk = 64 (2 mfma k-steps). LDS per buf: [hi 512 slots][lo 512 slots], slot(16B) = kq*64 + col.
__global__ __launch_bounds__(256) void gemm1_mfma_k(const float* __restrict__ x,
                                                    const unsigned short* __restrict__ wt_hi,
                                                    const unsigned short* __restrict__ wt_lo,
                                                    float* __restrict__ h, int N) {
    __shared__ alignas(16) unsigned short wlds[2][8192];   // 32 KB
    const int tid = threadIdx.x;
    const int wave = tid >> 6, lane = tid & 63;
    const int m = lane & 15, q = lane >> 4;
    const int row = blockIdx.x * 64 + wave * 16 + m;
    const int row_c = row < N ? row : N - 1;   // clamp: garbage lands in unstored rows
    const float* xp = x + (size_t)row_c * IN_F + q * 8;

    f32x4 acc[4];
#pragma unroll
    for (int ct = 0; ct < 4; ct++) acc[ct] = (f32x4){0.f, 0.f, 0.f, 0.f};
    float4 xr[2][4];

    // async W chunk load: 1024 slots of 16B by 256 threads, 4 insts each
#define WLOAD(c, buf)                                                                              \
    {                                                                                              \
        _Pragma("unroll") for (int j_ = 0; j_ < 4; j_++) {                                         \
            int slot_ = j_ * 256 + wave * 64 + lane;                                               \
            const unsigned short* gbase_ = (slot_ < 512) ? wt_hi : wt_lo;                          \
            int s_ = slot_ & 511;                                                                  \
            int col_ = s_ & 63, kq_ = s_ >> 6;                                                     \
            const unsigned short* g_ = gbase_ + (size_t)col_ * IN_F + (c) * 64 + kq_ * 8;          \
            unsigned short* l_ = &wlds[buf][0] + (size_t)(j_ * 256 + wave * 64) * 8;               \
            __builtin_amdgcn_global_load_lds((const __attribute__((address_space(1))) unsigned int*)g_, \
                                             (__attribute__((address_space(3))) unsigned int*)l_,  \
                                             16, 0, 0);                                            \
        }                                                                                          \
    }
#define XLOAD(c, r)                                  \
    {                                                \
        const float* xsrc_ = xp + (c) * 64;          \
        (r)[0] = *(const float4*)(xsrc_);            \
        (r)[1] = *(const float4*)(xsrc_ + 4);        \
        (r)[2] = *(const float4*)(xsrc_ + 32);       \
        (r)[3] = *(const float4*)(xsrc_ + 36);       \
    }

    WLOAD(0, 0);
    XLOAD(0, xr[0]);

    for (int c = 0; c < 8; c++) {
        int p = c & 1;
        __syncthreads();                      // drains chunk-c W + x (issued a full chunk ago)
        if (c < 7) {
            WLOAD(c + 1, p ^ 1);
            XLOAD(c + 1, xr[p ^ 1]);
        }
#pragma unroll
        for (int ki = 0; ki < 2; ki++) {
            // convert 8 floats -> a_hi (trunc pack via v_perm), a_lo (exact residual, trunc pack)
            float f[8];
            f[0] = xr[p][ki * 2].x; f[1] = xr[p][ki * 2].y; f[2] = xr[p][ki * 2].z; f[3] = xr[p][ki * 2].w;
            f[4] = xr[p][ki * 2 + 1].x; f[5] = xr[p][ki * 2 + 1].y; f[6] = xr[p][ki * 2 + 1].z; f[7] = xr[p][ki * 2 + 1].w;
            unsigned int u[8], lu[8];
#pragma unroll
            for (int j = 0; j < 8; j++) u[j] = __float_as_uint(f[j]);
            union { uint4 u4; bf16x8 v; } H, L;
            H.u4.x = __builtin_amdgcn_perm(u[1], u[0], 0x07060302u);
            H.u4.y = __builtin_amdgcn_perm(u[3], u[2], 0x07060302u);
            H.u4.z = __builtin_amdgcn_perm(u[5], u[4], 0x07060302u);
            H.u4.w = __builtin_amdgcn_perm(u[7], u[6], 0x07060302u);
#pragma unroll
            for (int j = 0; j < 8; j++)
                lu[j] = __float_as_uint(f[j] - __uint_as_float(u[j] & 0xFFFF0000u));
            L.u4.x = __builtin_amdgcn_perm(lu[1], lu[0], 0x07060302u);
            L.u4.y = __builtin_amdgcn_perm(lu[3], lu[2], 0x07060302u);
            L.u4.z = __builtin_amdgcn_perm(lu[5], lu[4], 0x07060302u);
            L.u4.w = __builtin_amdgcn_perm(lu[7], lu[6], 0x07060302u);
            int kq = ki * 4 + q;
#pragma unroll
            for (int ct = 0; ct < 4; ct++) {
                int slot = kq * 64 + ct * 16 + m;
                bf16x8 bh = *(const bf16x8*)&wlds[p][slot * 8];
                bf16x8 bl = *(const bf16x8*)&wlds[p][4096 + slot * 8];
                acc[ct] = __builtin_amdgcn_mfma_f32_16x16x32_bf16(H.v, bh, acc[ct], 0, 0, 0);
                acc[ct] = __builtin_amdgcn_mfma_f32_16x16x32_bf16(L.v, bh, acc[ct], 0, 0, 0);
                acc[ct] = __builtin_amdgcn_mfma_f32_16x16x32_bf16(H.v, bl, acc[ct], 0, 0, 0);
            }
        }
    }
    int rbase = blockIdx.x * 64 + wave * 16 + q * 4;
#pragma unroll
    for (int r = 0; r < 4; r++) {
        int ro = rbase + r;
        if (ro < N) {
#pragma unroll
            for (int ct = 0; ct < 4; ct++)
                h[(size_t)ro * C1 + ct * 16 + m] = acc[ct][r];
        }
    }
#undef WLOAD
#undef XLOAD
}

// ---------------- attn coefs layer1: el/er[N,8] ----------------
__global__ __launch_bounds__(256) void attn1_k(const float* __restrict__ h, const float* __restrict__ al,
                                               const float* __restrict__ ar, float* __restrict__ el,
                                               float* __restrict__ er, int N) {
    int idx = blockIdx.x * 256 + threadIdx.x;
    if (idx >= N * NH) return;
    int n = idx >> 3, hd = idx & 7;
    const float4* hp = (const float4*)(h + (size_t)n * C1 + hd * FD);
    const float4* alp = (const float4*)(al + hd * FD);
    const float4* arp = (const float4*)(ar + hd * FD);
    float4 v0 = hp[0], v1 = hp[1];
    float4 a0 = alp[0], a1 = alp[1];
    float4 r0 = arp[0], r1 = arp[1];
    float e_l = v0.x * a0.x + v0.y * a0.y + v0.z * a0.z + v0.w * a0.w +
                v1.x * a1.x + v1.y * a1.y + v1.z * a1.z + v1.w * a1.w;
    float e_r = v0.x * r0.x + v0.y * r0.y + v0.z * r0.z + v0.w * r0.w +
                v1.x * r1.x + v1.y * r1.y + v1.z * r1.z + v1.w * r1.w;
    el[idx] = e_l;
    er[idx] = e_r;
}

// ---------------- layer1 fused: single-pass edge softmax-agg + bias + elu + GEMM2 + attn2 ----------------
__global__ __launch_bounds__(256) void l1_agg_k(const float* __restrict__ h,
                                                const float* __restrict__ el, const float* __restrict__ er,
                                                const int* __restrict__ rowp, const int* __restrict__ deg,
                                                const int* __restrict__ csr_src, const float* __restrict__ b1,
                                                const float* __restrict__ W2, const float* __restrict__ al2,
                                                const float* __restrict__ ar2,
                                                float* __restrict__ h2pre, float* __restrict__ el2o,
                                                float* __restrict__ er2o, int N) {
    __shared__ float ws[C1 * C2];       // W2: 64x40
    __shared__ float hs[32][C1];        // h1 tile
    __shared__ float h2s[32][C2];       // h2 tile
    __shared__ float a2s[2 * C2];
    int tid = threadIdx.x;
    for (int i = tid; i < C1 * C2; i += 256) ws[i] = W2[i];
    if (tid < C2) a2s[tid] = al2[tid];
    else if (tid < 2 * C2) a2s[tid] = ar2[tid - C2];

    int n0 = blockIdx.x * 32;
    int ln = tid >> 3;
    int hd = tid & 7;
    int n = n0 + ln;
    float4 acc0 = make_float4(0.f, 0.f, 0.f, 0.f);
    float4 acc1 = make_float4(0.f, 0.f, 0.f, 0.f);
    float s = 0.f;
    if (n < N) {
        int start = rowp[n], cnt = deg[n];
        float erd = er[n * NH + hd];
        int i = 0;
        for (; i + 1 < cnt; i += 2) {
            int sn0 = csr_src[start + i];
            int sn1 = csr_src[start + i + 1];
            float e0 = el[sn0 * NH + hd] + erd;
            float e1 = el[sn1 * NH + hd] + erd;
            e0 = e0 > 0.f ? e0 : NEG * e0;
            e1 = e1 > 0.f ? e1 : NEG * e1;
            float w0 = __expf(e0), w1 = __expf(e1);
            s += w0 + w1;
            const float4* hp0 = (const float4*)(h + (size_t)sn0 * C1 + hd * FD);
            const float4* hp1 = (const float4*)(h + (size_t)sn1 * C1 + hd * FD);
            float4 v00 = hp0[0], v01 = hp0[1];
            float4 v10 = hp1[0], v11 = hp1[1];
            acc0.x += w0 * v00.x + w1 * v10.x; acc0.y += w0 * v00.y + w1 * v10.y;
            acc0.z += w0 * v00.z + w1 * v10.z; acc0.w += w0 * v00.w + w1 * v10.w;
            acc1.x += w0 * v01.x + w1 * v11.x; acc1.y += w0 * v01.y + w1 * v11.y;
            acc1.z += w0 * v01.z + w1 * v11.z; acc1.w += w0 * v01.w + w1 * v11.w;
        }
        if (i < cnt) {
            int sn = csr_src[start + i];
            float e = el[sn * NH + hd] + erd;
            e = e > 0.f ? e : NEG * e;
            float w0 = __expf(e);
            s += w0;
            const float4* hp = (const float4*)(h + (size_t)sn * C1 + hd * FD);
            float4 v0 = hp[0], v1 = hp[1];
            acc0.x += w0 * v0.x; acc0.y += w0 * v0.y; acc0.z += w0 * v0.z; acc0.w += w0 * v0.w;
            acc1.x += w0 * v1.x; acc1.y += w0 * v1.y; acc1.z += w0 * v1.z; acc1.w += w0 * v1.w;
        }
    }
    float sinv = (s > 0.f) ? 1.f / s : 0.f;
    const float4* bp = (const float4*)(b1 + hd * FD);
    float4 bb0 = bp[0], bb1 = bp[1];
    float o[8] = {acc0.x * sinv + bb0.x, acc0.y * sinv + bb0.y, acc0.z * sinv + bb0.z, acc0.w * sinv + bb0.w,
                  acc1.x * sinv + bb1.x, acc1.y * sinv + bb1.y, acc1.z * sinv + bb1.z, acc1.w * sinv + bb1.w};
#pragma unroll
    for (int f = 0; f < 8; f++) o[f] = o[f] > 0.f ? o[f] : (__expf(o[f]) - 1.f);  // elu
    *(float4*)&hs[ln][hd * FD] = make_float4(o[0], o[1], o[2], o[3]);
    *(float4*)&hs[ln][hd * FD + 4] = make_float4(o[4], o[5], o[6], o[7]);
    __syncthreads();

    // GEMM2 tile: h2s[32][40] = hs[32][64] @ ws[64][40]
    for (int oidx = tid; oidx < 32 * C2; oidx += 256) {
        int r = oidx / C2, c = oidx % C2;
        float sum = 0.f;
#pragma unroll
        for (int k = 0; k < C1; k++) sum += hs[r][k] * ws[k * C2 + c];
        h2s[r][c] = sum;
        int nn = n0 + r;
        if (nn < N) h2pre[(size_t)nn * C2 + c] = sum;
    }
    __syncthreads();

    // attn2 for this tile's nodes
    if (tid < 32) {
        int nn = n0 + tid;
        if (nn < N) {
            float e_l = 0.f, e_r = 0.f;
#pragma unroll
            for (int c = 0; c < C2; c++) {
                float v = h2s[tid][c];
                e_l += v * a2s[c];
                e_r += v * a2s[C2 + c];
            }
            el2o[nn] = e_l;
            er2o[nn] = e_r;
        }
    }
}

// ---------------- layer2 fused: 8 lanes per node, coalesced h2 row gathers ----------------
__global__ __launch_bounds__(256) void l2_fused_k(const float* __restrict__ h2, const float* __restrict__ el,
                                                  const float* __restrict__ er, const int* __restrict__ rowp,
                                                  const int* __restrict__ deg, const int* __restrict__ csr_src,
                                                  const float* __restrict__ b2, float* __restrict__ out, int N) {
    int tid = threadIdx.x;
    int n = blockIdx.x * 32 + (tid >> 3);
    int sub = tid & 7;
    if (n >= N) return;
    int start = rowp[n], cnt = deg[n];
    float erd = er[n];
    float s = 0.f;
    float4 a4 = make_float4(0.f, 0.f, 0.f, 0.f);
    float a1 = 0.f;
    int i = 0;
    for (; i + 1 < cnt; i += 2) {
        int sn0 = csr_src[start + i];
        int sn1 = csr_src[start + i + 1];
        float e0 = el[sn0] + erd, e1 = el[sn1] + erd;
        e0 = e0 > 0.f ? e0 : NEG * e0;
        e1 = e1 > 0.f ? e1 : NEG * e1;
        float w0 = __expf(e0), w1 = __expf(e1);
        s += w0 + w1;
        const float* hp0 = h2 + (size_t)sn0 * C2;
        const float* hp1 = h2 + (size_t)sn1 * C2;
        float4 v0 = *(const float4*)(hp0 + sub * 4);
        float4 v1 = *(const float4*)(hp1 + sub * 4);
        float s0 = hp0[32 + sub], s1 = hp1[32 + sub];
        a4.x += w0 * v0.x + w1 * v1.x; a4.y += w0 * v0.y + w1 * v1.y;
        a4.z += w0 * v0.z + w1 * v1.z; a4.w += w0 * v0.w + w1 * v1.w;
        a1 += w0 * s0 + w1 * s1;
    }
    if (i < cnt) {
        int sn = csr_src[start + i];
        float e = el[sn] + erd;
        e = e > 0.f ? e : NEG * e;
        float w0 = __expf(e);
        s += w0;
        const float* hp = h2 + (size_t)sn * C2;
        float4 v = *(const float4*)(hp + sub * 4);
        a4.x += w0 * v.x; a4.y += w0 * v.y; a4.z += w0 * v.z; a4.w += w0 * v.w;
        a1 += w0 * hp[32 + sub];
    }
    float sinv = (s > 0.f) ? 1.f / s : 0.f;
    float4 bb = *(const float4*)(b2 + sub * 4);
    a4.x = a4.x * sinv + bb.x; a4.y = a4.y * sinv + bb.y;
    a4.z = a4.z * sinv + bb.z; a4.w = a4.w * sinv + bb.w;
    a1 = a1 * sinv + b2[32 + sub];
    // log_softmax over the node's 40 values (spread 5-per-lane over 8 lanes)
    float mx = fmaxf(fmaxf(fmaxf(a4.x, a4.y), fmaxf(a4.z, a4.w)), a1);
#pragma unroll
    for (int off = 1; off < 8; off <<= 1) mx = fmaxf(mx, __shfl_xor(mx, off, 8));
    float se = __expf(a4.x - mx) + __expf(a4.y - mx) + __expf(a4.z - mx) + __expf(a4.w - mx) + __expf(a1 - mx);
#pragma unroll
    for (int off = 1; off < 8; off <<= 1) se += __shfl_xor(se, off, 8);
    float ls = __logf(se) + mx;
    float* op = out + (size_t)n * C2;
    *(float4*)(op + sub * 4) = make_float4(a4.x - ls, a4.y - ls, a4.z - ls, a4.w - ls);
    op[32 + sub] = a1 - ls;
}

extern "C" void kernel_launch(void* const* d_in, const int* in_sizes, int n_in,
                              void* d_out, int out_size, void* d_ws, size_t ws_size,
                              hipStream_t stream) {
    (void)n_in; (void)out_size; (void)ws_size;
    const float* x   = (const float*)d_in[0];
    const int*   src = (const int*)d_in[1];
    const int*   dst = (const int*)d_in[2];
    const float* W1  = (const float*)d_in[3];
    const float* al1 = (const float*)d_in[4];
    const float* ar1 = (const float*)d_in[5];
    const float* b1  = (const float*)d_in[6];
    const float* W2  = (const float*)d_in[7];
    const float* al2 = (const float*)d_in[8];
    const float* ar2 = (const float*)d_in[9];
    const float* b2  = (const float*)d_in[10];
    float* out = (float*)d_out;
    const int N = in_sizes[0] / IN_F;
    const int E = in_sizes[1];

    char* w = (char*)d_ws;
    auto alloc = [&](size_t bytes) -> char* {
        char* p = w;
        w += (bytes + 255) & ~(size_t)255;
        return p;
    };
    int* deg     = (int*)alloc((size_t)N * 4);
    int* fill    = (int*)alloc((size_t)N * 4);
    int* rowp    = (int*)alloc((size_t)N * 4);
    int* bsums   = (int*)alloc(512);
    int* csr_src = (int*)alloc((size_t)E * 4);
    unsigned short* wt_hi = (unsigned short*)alloc((size_t)IN_F * C1 * 2);
    unsigned short* wt_lo = (unsigned short*)alloc((size_t)IN_F * C1 * 2);
    float* h1pre = (float*)alloc((size_t)N * C1 * 4);
    float* el1   = (float*)alloc((size_t)N * NH * 4);
    float* er1   = (float*)alloc((size_t)N * NH * 4);
    float* h2pre = (float*)alloc((size_t)N * C2 * 4);
    float* el2   = (float*)alloc((size_t)N * 4);
    float* er2   = (float*)alloc((size_t)N * 4);

    hipMemsetAsync(deg, 0, (size_t)N * 4, stream);
    hipMemsetAsync(fill, 0, (size_t)N * 4, stream);

    int ebl = (E + 255) / 256;
    int nb = (N + 1023) / 1024;
    hist_k<<<ebl, 256, 0, stream>>>(dst, deg, E);
    scan_local_k<<<nb, 1024, 0, stream>>>(deg, rowp, bsums, N);
    scan_sums_k<<<1, 128, 0, stream>>>(bsums, nb);
    scan_add_k<<<nb, 1024, 0, stream>>>(rowp, bsums, N);
    scatter_k<<<ebl, 256, 0, stream>>>(src, dst, rowp, fill, csr_src, E);

    wt_pre_k<<<(IN_F * C1 + 255) / 256, 256, 0, stream>>>(W1, wt_hi, wt_lo);
    gemm1_mfma_k<<<(N + 63) / 64, 256, 0, stream>>>(x, wt_hi, wt_lo, h1pre, N);
    attn1_k<<<(N * NH + 255) / 256, 256, 0, stream>>>(h1pre, al1, ar1, el1, er1, N);
    l1_agg_k<<<(N + 31) / 32, 256, 0, stream>>>(h1pre, el1, er1, rowp, deg, csr_src, b1,
                                                W2, al2, ar2, h2pre, el2, er2, N);
    l2_fused_k<<<(N + 31) / 32, 256, 0, stream>>>(h2pre, el2, er2, rowp, deg, csr_src, b2, out, N);
}

// Round 5
// 635.631 us; speedup vs baseline: 1.1971x; 1.0209x over previous
//
#include <hip/hip_runtime.h>
#include <cstdint>
#include <cstddef>

#define IN_F 512
#define C1 64      // H1*F1
#define NH 8
#define FD 8
#define C2 40
#define NEG 0.2f

typedef __attribute__((ext_vector_type(8))) short bf16x8;
typedef __attribute__((ext_vector_type(4))) float f32x4;

__device__ inline unsigned short f32_to_bf16_rne(float f) {
    unsigned int u = __float_as_uint(f);
    unsigned int r = (u + 0x7FFFu + ((u >> 16) & 1u)) >> 16;
    return (unsigned short)r;
}
__device__ inline float bf16_to_f32(unsigned short s) {
    return __uint_as_float(((unsigned int)s) << 16);
}

// ---------------- CSR build ----------------
// hist also records each edge's rank among its dst's edges (atomic return value)
__global__ __launch_bounds__(256) void hist_k(const int* __restrict__ dst, int* __restrict__ deg,
                                              int* __restrict__ pos, int E) {
    int e = blockIdx.x * 256 + threadIdx.x;
    if (e < E) pos[e] = atomicAdd(&deg[dst[e]], 1);
}

__global__ __launch_bounds__(1024) void scan_local_k(const int* __restrict__ deg, int* __restrict__ rowp,
                                                     int* __restrict__ bsums, int n) {
    __shared__ int tmp[1024];
    int tx = threadIdx.x;
    int i = blockIdx.x * 1024 + tx;
    int v = (i < n) ? deg[i] : 0;
    tmp[tx] = v;
    __syncthreads();
    for (int d = 1; d < 1024; d <<= 1) {
        int t = (tx >= d) ? tmp[tx - d] : 0;
        __syncthreads();
        tmp[tx] += t;
        __syncthreads();
    }
    if (i < n) rowp[i] = tmp[tx] - v;   // exclusive within block
    if (tx == 1023) bsums[blockIdx.x] = tmp[tx];
}

__global__ __launch_bounds__(128) void scan_sums_k(int* bsums, int nb) {
    __shared__ int tmp[128];
    int tx = threadIdx.x;
    int v = (tx < nb) ? bsums[tx] : 0;
    tmp[tx] = v;
    __syncthreads();
    for (int d = 1; d < 128; d <<= 1) {
        int t = (tx >= d) ? tmp[tx - d] : 0;
        __syncthreads();
        tmp[tx] += t;
        __syncthreads();
    }
    if (tx < nb) bsums[tx] = tmp[tx] - v;  // exclusive
}

__global__ __launch_bounds__(1024) void scan_add_k(int* rowp, const int* __restrict__ bsums, int n) {
    int i = blockIdx.x * 1024 + threadIdx.x;
    if (i < n) rowp[i] += bsums[blockIdx.x];
}

// atomic-free scatter using precomputed rank
__global__ __launch_bounds__(256) void scatter_k(const int* __restrict__ src, const int* __restrict__ dst,
                                                 const int* __restrict__ rowp, const int* __restrict__ pos,
                                                 int* __restrict__ csr_src, int E) {
    int e = blockIdx.x * 256 + threadIdx.x;
    if (e >= E) return;
    csr_src[rowp[dst[e]] + pos[e]] = src[e];
}

// ---------------- W1 preconvert: Wt_hi/Wt_lo[col][k] split-bf16 ----------------
__global__ __launch_bounds__(256) void wt_pre_k(const float* __restrict__ W1,
                                                unsigned short* __restrict__ wt_hi,
                                                unsigned short* __restrict__ wt_lo) {
    int id = blockIdx.x * 256 + threadIdx.x;   // id over 512*64
    if (id >= IN_F * C1) return;
    int col = id & (C1 - 1);
    int k = id >> 6;
    float w = W1[id];
    unsigned short hb = f32_to_bf16_rne(w);
    unsigned short lb = f32_to_bf16_rne(w - bf16_to_f32(hb));
    wt_hi[(size_t)col * IN_F + k] = hb;
    wt_lo[(size_t)col * IN_F + k] = lb;
}

// ---------------- GEMM1 via split-bf16 MFMA, W staged in LDS (async, dbuf), x reg-prefetch ----------------
__global__ __launch_bounds__(256) void gemm1_mfma_k(const float* __restrict__ x,
                                                    const unsigned short* __restrict__ wt_hi,
                                                    const unsigned short* __restrict__ wt_lo,
                                                    float* __restrict__ h, int N) {
    __shared__ alignas(16) unsigned short wlds[2][8192];   // 32 KB
    const int tid = threadIdx.x;
    const int wave = tid >> 6, lane = tid & 63;
    const int m = lane & 15, q = lane >> 4;
    const int row = blockIdx.x * 64 + wave * 16 + m;
    const int row_c = row < N ? row : N - 1;   // clamp: garbage lands in unstored rows
    const float* xp = x + (size_t)row_c * IN_F + q * 8;

    f32x4 acc[4];
#pragma unroll
    for (int ct = 0; ct < 4; ct++) acc[ct] = (f32x4){0.f, 0.f, 0.f, 0.f};
    float4 xr[2][4];

#define WLOAD(c, buf)                                                                              \
    {                                                                                              \
        _Pragma("unroll") for (int j_ = 0; j_ < 4; j_++) {                                         \
            int slot_ = j_ * 256 + wave * 64 + lane;                                               \
            const unsigned short* gbase_ = (slot_ < 512) ? wt_hi : wt_lo;                          \
            int s_ = slot_ & 511;                                                                  \
            int col_ = s_ & 63, kq_ = s_ >> 6;                                                     \
            const unsigned short* g_ = gbase_ + (size_t)col_ * IN_F + (c) * 64 + kq_ * 8;          \
            unsigned short* l_ = &wlds[buf][0] + (size_t)(j_ * 256 + wave * 64) * 8;               \
            __builtin_amdgcn_global_load_lds((const __attribute__((address_space(1))) unsigned int*)g_, \
                                             (__attribute__((address_space(3))) unsigned int*)l_,  \
                                             16, 0, 0);                                            \
        }                                                                                          \
    }
#define XLOAD(c, r)                                  \
    {                                                \
        const float* xsrc_ = xp + (c) * 64;          \
        (r)[0] = *(const float4*)(xsrc_);            \
        (r)[1] = *(const float4*)(xsrc_ + 4);        \
        (r)[2] = *(const float4*)(xsrc_ + 32);       \
        (r)[3] = *(const float4*)(xsrc_ + 36);       \
    }

    WLOAD(0, 0);
    XLOAD(0, xr[0]);

    for (int c = 0; c < 8; c++) {
        int p = c & 1;
        __syncthreads();                      // drains chunk-c W + x (issued a full chunk ago)
        if (c < 7) {
            WLOAD(c + 1, p ^ 1);
            XLOAD(c + 1, xr[p ^ 1]);
        }
#pragma unroll
        for (int ki = 0; ki < 2; ki++) {
            float f[8];
            f[0] = xr[p][ki * 2].x; f[1] = xr[p][ki * 2].y; f[2] = xr[p][ki * 2].z; f[3] = xr[p][ki * 2].w;
            f[4] = xr[p][ki * 2 + 1].x; f[5] = xr[p][ki * 2 + 1].y; f[6] = xr[p][ki * 2 + 1].z; f[7] = xr[p][ki * 2 + 1].w;
            unsigned int u[8], lu[8];
#pragma unroll
            for (int j = 0; j < 8; j++) u[j] = __float_as_uint(f[j]);
            union { uint4 u4; bf16x8 v; } H, L;
            H.u4.x = __builtin_amdgcn_perm(u[1], u[0], 0x07060302u);
            H.u4.y = __builtin_amdgcn_perm(u[3], u[2], 0x07060302u);
            H.u4.z = __builtin_amdgcn_perm(u[5], u[4], 0x07060302u);
            H.u4.w = __builtin_amdgcn_perm(u[7], u[6], 0x07060302u);
#pragma unroll
            for (int j = 0; j < 8; j++)
                lu[j] = __float_as_uint(f[j] - __uint_as_float(u[j] & 0xFFFF0000u));
            L.u4.x = __builtin_amdgcn_perm(lu[1], lu[0], 0x07060302u);
            L.u4.y = __builtin_amdgcn_perm(lu[3], lu[2], 0x07060302u);
            L.u4.z = __builtin_amdgcn_perm(lu[5], lu[4], 0x07060302u);
            L.u4.w = __builtin_amdgcn_perm(lu[7], lu[6], 0x07060302u);
            int kq = ki * 4 + q;
#pragma unroll
            for (int ct = 0; ct < 4; ct++) {
                int slot = kq * 64 + ct * 16 + m;
                bf16x8 bh = *(const bf16x8*)&wlds[p][slot * 8];
                bf16x8 bl = *(const bf16x8*)&wlds[p][4096 + slot * 8];
                acc[ct] = __builtin_amdgcn_mfma_f32_16x16x32_bf16(H.v, bh, acc[ct], 0, 0, 0);
                acc[ct] = __builtin_amdgcn_mfma_f32_16x16x32_bf16(L.v, bh, acc[ct], 0, 0, 0);
                acc[ct] = __builtin_amdgcn_mfma_f32_16x16x32_bf16(H.v, bl, acc[ct], 0, 0, 0);
            }
        }
    }
    int rbase = blockIdx.x * 64 + wave * 16 + q * 4;
#pragma unroll
    for (int r = 0; r < 4; r++) {
        int ro = rbase + r;
        if (ro < N) {
#pragma unroll
            for (int ct = 0; ct < 4; ct++)
                h[(size_t)ro * C1 + ct * 16 + m] = acc[ct][r];
        }
    }
#undef WLOAD
#undef XLOAD
}

// ---------------- attn coefs layer1: el/er[N,8] ----------------
__global__ __launch_bounds__(256) void attn1_k(const float* __restrict__ h, const float* __restrict__ al,
                                               const float* __restrict__ ar, float* __restrict__ el,
                                               float* __restrict__ er, int N) {
    int idx = blockIdx.x * 256 + threadIdx.x;
    if (idx >= N * NH) return;
    int n = idx >> 3, hd = idx & 7;
    const float4* hp = (const float4*)(h + (size_t)n * C1 + hd * FD);
    const float4* alp = (const float4*)(al + hd * FD);
    const float4* arp = (const float4*)(ar + hd * FD);
    float4 v0 = hp[0], v1 = hp[1];
    float4 a0 = alp[0], a1 = alp[1];
    float4 r0 = arp[0], r1 = arp[1];
    float e_l = v0.x * a0.x + v0.y * a0.y + v0.z * a0.z + v0.w * a0.w +
                v1.x * a1.x + v1.y * a1.y + v1.z * a1.z + v1.w * a1.w;
    float e_r = v0.x * r0.x + v0.y * r0.y + v0.z * r0.z + v0.w * r0.w +
                v1.x * r1.x + v1.y * r1.y + v1.z * r1.z + v1.w * r1.w;
    el[idx] = e_l;
    er[idx] = e_r;
}

// ---------------- layer1: ONE WAVE PER NODE. lane = head*8 + feat ----------------
// Per edge: 1 coalesced 256B h-row load + 1 broadcast 32B el-row load. Batch-4 ILP.
__global__ __launch_bounds__(256) void l1_wave_k(const float* __restrict__ h,
                                                 const float* __restrict__ el, const float* __restrict__ er,
                                                 const int* __restrict__ rowp, const int* __restrict__ deg,
                                                 const int* __restrict__ csr_src, const float* __restrict__ b1,
                                                 float* __restrict__ h1out, int N) {
    int n = (blockIdx.x * 256 + threadIdx.x) >> 6;   // node = global wave id
    if (n >= N) return;
    int lane = threadIdx.x & 63;
    int hg = lane >> 3;                              // head
    int start = rowp[n], cnt = deg[n];
    float erd = er[n * NH + hg];
    float acc = 0.f, s = 0.f;
    int i = 0;
    for (; i + 4 <= cnt; i += 4) {
        const int* cp = csr_src + start + i;
        int sn0 = cp[0], sn1 = cp[1], sn2 = cp[2], sn3 = cp[3];
        float e0 = el[sn0 * NH + hg];
        float e1 = el[sn1 * NH + hg];
        float e2 = el[sn2 * NH + hg];
        float e3 = el[sn3 * NH + hg];
        float v0 = h[(size_t)sn0 * C1 + lane];
        float v1 = h[(size_t)sn1 * C1 + lane];
        float v2 = h[(size_t)sn2 * C1 + lane];
        float v3 = h[(size_t)sn3 * C1 + lane];
        e0 += erd; e1 += erd; e2 += erd; e3 += erd;
        e0 = e0 > 0.f ? e0 : NEG * e0;
        e1 = e1 > 0.f ? e1 : NEG * e1;
        e2 = e2 > 0.f ? e2 : NEG * e2;
        e3 = e3 > 0.f ? e3 : NEG * e3;
        float w0 = __expf(e0), w1 = __expf(e1), w2 = __expf(e2), w3 = __expf(e3);
        s += (w0 + w1) + (w2 + w3);
        acc += w0 * v0 + w1 * v1 + w2 * v2 + w3 * v3;
    }
    for (; i < cnt; i++) {
        int sn = csr_src[start + i];
        float e = el[sn * NH + hg] + erd;
        e = e > 0.f ? e : NEG * e;
        float w0 = __expf(e);
        s += w0;
        acc += w0 * h[(size_t)sn * C1 + lane];
    }
    float sinv = (s > 0.f) ? 1.f / s : 0.f;
    float o = acc * sinv + b1[lane];
    o = o > 0.f ? o : (__expf(o) - 1.f);   // elu
    h1out[(size_t)n * C1 + lane] = o;
}

// ---------------- GEMM2 + attn2 fused: h2pre[N,40] = h1[N,64] @ W2; el2/er2 ----------------
__global__ __launch_bounds__(256) void gemm2_attn2_k(const float* __restrict__ h1, const float* __restrict__ W2,
                                                     const float* __restrict__ al2, const float* __restrict__ ar2,
                                                     float* __restrict__ h2pre, float* __restrict__ el2,
                                                     float* __restrict__ er2, int N) {
    __shared__ float ws[C1 * C2];   // 10 KB
    __shared__ float hs[64][C1];    // 16 KB
    __shared__ float h2s[64][C2];   // 10 KB
    __shared__ float a2s[2 * C2];
    int t = threadIdx.x;
    int n0 = blockIdx.x * 64;
    for (int i = t; i < C1 * C2; i += 256) ws[i] = W2[i];
    if (t < C2) a2s[t] = al2[t];
    else if (t < 2 * C2) a2s[t] = ar2[t - C2];
    for (int i = t; i < 64 * 16; i += 256) {
        int r = i >> 4, c4 = i & 15;
        int n = n0 + r;
        float4 v = (n < N) ? *(const float4*)(h1 + (size_t)n * C1 + c4 * 4) : make_float4(0.f, 0.f, 0.f, 0.f);
        *(float4*)&hs[r][c4 * 4] = v;
    }
    __syncthreads();
    for (int o = t; o < 64 * C2; o += 256) {
        int r = o / C2, c = o % C2;
        float sum = 0.f;
#pragma unroll
        for (int k = 0; k < C1; k++) sum += hs[r][k] * ws[k * C2 + c];
        h2s[r][c] = sum;
        int nn = n0 + r;
        if (nn < N) h2pre[(size_t)nn * C2 + c] = sum;
    }
    __syncthreads();
    if (t < 64) {
        int nn = n0 + t;
        if (nn < N) {
            float e_l = 0.f, e_r = 0.f;
#pragma unroll
            for (int c = 0; c < C2; c++) {
                float v = h2s[t][c];
                e_l += v * a2s[c];
                e_r += v * a2s[C2 + c];
            }
            el2[nn] = e_l;
            er2[nn] = e_r;
        }
    }
}

// ---------------- layer2 fused: 8 lanes per node, batch-4 edge ILP ----------------
__global__ __launch_bounds__(256) void l2_fused_k(const float* __restrict__ h2, const float* __restrict__ el,
                                                  const float* __restrict__ er, const int* __restrict__ rowp,
                                                  const int* __restrict__ deg, const int* __restrict__ csr_src,
                                                  const float* __restrict__ b2, float* __restrict__ out, int N) {
    int tid = threadIdx.x;
    int n = blockIdx.x * 32 + (tid >> 3);
    int sub = tid & 7;
    if (n >= N) return;
    int start = rowp[n], cnt = deg[n];
    float erd = er[n];
    float s = 0.f;
    float4 a4 = make_float4(0.f, 0.f, 0.f, 0.f);
    float a1 = 0.f;
    int i = 0;
    for (; i + 4 <= cnt; i += 4) {
        const int* cp = csr_src + start + i;
        int sn0 = cp[0], sn1 = cp[1], sn2 = cp[2], sn3 = cp[3];
        float e0 = el[sn0], e1 = el[sn1], e2 = el[sn2], e3 = el[sn3];
        const float* hp0 = h2 + (size_t)sn0 * C2;
        const float* hp1 = h2 + (size_t)sn1 * C2;
        const float* hp2 = h2 + (size_t)sn2 * C2;
        const float* hp3 = h2 + (size_t)sn3 * C2;
        float4 v0 = *(const float4*)(hp0 + sub * 4);
        float4 v1 = *(const float4*)(hp1 + sub * 4);
        float4 v2 = *(const float4*)(hp2 + sub * 4);
        float4 v3 = *(const float4*)(hp3 + sub * 4);
        float s0 = hp0[32 + sub], s1 = hp1[32 + sub], s2 = hp2[32 + sub], s3 = hp3[32 + sub];
        e0 += erd; e1 += erd; e2 += erd; e3 += erd;
        e0 = e0 > 0.f ? e0 : NEG * e0;
        e1 = e1 > 0.f ? e1 : NEG * e1;
        e2 = e2 > 0.f ? e2 : NEG * e2;
        e3 = e3 > 0.f ? e3 : NEG * e3;
        float w0 = __expf(e0), w1 = __expf(e1), w2 = __expf(e2), w3 = __expf(e3);
        s += (w0 + w1) + (w2 + w3);
        a4.x += w0 * v0.x + w1 * v1.x + w2 * v2.x + w3 * v3.x;
        a4.y += w0 * v0.y + w1 * v1.y + w2 * v2.y + w3 * v3.y;
        a4.z += w0 * v0.z + w1 * v1.z + w2 * v2.z + w3 * v3.z;
        a4.w += w0 * v0.w + w1 * v1.w + w2 * v2.w + w3 * v3.w;
        a1 += w0 * s0 + w1 * s1 + w2 * s2 + w3 * s3;
    }
    for (; i < cnt; i++) {
        int sn = csr_src[start + i];
        float e = el[sn] + erd;
        e = e > 0.f ? e : NEG * e;
        float w0 = __expf(e);
        s += w0;
        const float* hp = h2 + (size_t)sn * C2;
        float4 v = *(const float4*)(hp + sub * 4);
        a4.x += w0 * v.x; a4.y += w0 * v.y; a4.z += w0 * v.z; a4.w += w0 * v.w;
        a1 += w0 * hp[32 + sub];
    }
    float sinv = (s > 0.f) ? 1.f / s : 0.f;
    float4 bb = *(const float4*)(b2 + sub * 4);
    a4.x = a4.x * sinv + bb.x; a4.y = a4.y * sinv + bb.y;
    a4.z = a4.z * sinv + bb.z; a4.w = a4.w * sinv + bb.w;
    a1 = a1 * sinv + b2[32 + sub];
    float mx = fmaxf(fmaxf(fmaxf(a4.x, a4.y), fmaxf(a4.z, a4.w)), a1);
#pragma unroll
    for (int off = 1; off < 8; off <<= 1) mx = fmaxf(mx, __shfl_xor(mx, off, 8));
    float se = __expf(a4.x - mx) + __expf(a4.y - mx) + __expf(a4.z - mx) + __expf(a4.w - mx) + __expf(a1 - mx);
#pragma unroll
    for (int off = 1; off < 8; off <<= 1) se += __shfl_xor(se, off, 8);
    float ls = __logf(se) + mx;
    float* op = out + (size_t)n * C2;
    *(float4*)(op + sub * 4) = make_float4(a4.x - ls, a4.y - ls, a4.z - ls, a4.w - ls);
    op[32 + sub] = a1 - ls;
}

extern "C" void kernel_launch(void* const* d_in, const int* in_sizes, int n_in,
                              void* d_out, int out_size, void* d_ws, size_t ws_size,
                              hipStream_t stream) {
    (void)n_in; (void)out_size; (void)ws_size;
    const float* x   = (const float*)d_in[0];
    const int*   src = (const int*)d_in[1];
    const int*   dst = (const int*)d_in[2];
    const float* W1  = (const float*)d_in[3];
    const float* al1 = (const float*)d_in[4];
    const float* ar1 = (const float*)d_in[5];
    const float* b1  = (const float*)d_in[6];
    const float* W2  = (const float*)d_in[7];
    const float* al2 = (const float*)d_in[8];
    const float* ar2 = (const float*)d_in[9];
    const float* b2  = (const float*)d_in[10];
    float* out = (float*)d_out;
    const int N = in_sizes[0] / IN_F;
    const int E = in_sizes[1];

    char* w = (char*)d_ws;
    auto alloc = [&](size_t bytes) -> char* {
        char* p = w;
        w += (bytes + 255) & ~(size_t)255;
        return p;
    };
    int* deg     = (int*)alloc((size_t)N * 4);
    int* rowp    = (int*)alloc((size_t)N * 4);
    int* bsums   = (int*)alloc(512);
    int* pos     = (int*)alloc((size_t)E * 4);
    int* csr_src = (int*)alloc((size_t)E * 4);
    unsigned short* wt_hi = (unsigned short*)alloc((size_t)IN_F * C1 * 2);
    unsigned short* wt_lo = (unsigned short*)alloc((size_t)IN_F * C1 * 2);
    float* h1pre = (float*)alloc((size_t)N * C1 * 4);
    float* el1   = (float*)alloc((size_t)N * NH * 4);
    float* er1   = (float*)alloc((size_t)N * NH * 4);
    float* h1    = (float*)alloc((size_t)N * C1 * 4);
    float* h2pre = (float*)alloc((size_t)N * C2 * 4);
    float* el2   = (float*)alloc((size_t)N * 4);
    float* er2   = (float*)alloc((size_t)N * 4);

    hipMemsetAsync(deg, 0, (size_t)N * 4, stream);

    int ebl = (E + 255) / 256;
    int nb = (N + 1023) / 1024;
    hist_k<<<ebl, 256, 0, stream>>>(dst, deg, pos, E);
    scan_local_k<<<nb, 1024, 0, stream>>>(deg, rowp, bsums, N);
    scan_sums_k<<<1, 128, 0, stream>>>(bsums, nb);
    scan_add_k<<<nb, 1024, 0, stream>>>(rowp, bsums, N);
    scatter_k<<<ebl, 256, 0, stream>>>(src, dst, rowp, pos, csr_src, E);

    wt_pre_k<<<(IN_F * C1 + 255) / 256, 256, 0, stream>>>(W1, wt_hi, wt_lo);
    gemm1_mfma_k<<<(N + 63) / 64, 256, 0, stream>>>(x, wt_hi, wt_lo, h1pre, N);
    attn1_k<<<(N * NH + 255) / 256, 256, 0, stream>>>(h1pre, al1, ar1, el1, er1, N);
    l1_wave_k<<<(N * 64 + 255) / 256, 256, 0, stream>>>(h1pre, el1, er1, rowp, deg, csr_src, b1, h1, N);
    gemm2_attn2_k<<<(N + 63) / 64, 256, 0, stream>>>(h1, W2, al2, ar2, h2pre, el2, er2, N);
    l2_fused_k<<<(N + 31) / 32, 256, 0, stream>>>(h2pre, el2, er2, rowp, deg, csr_src, b2, out, N);
}

// Round 6
// 612.706 us; speedup vs baseline: 1.2419x; 1.0374x over previous
//
#include <hip/hip_runtime.h>
#include <cstdint>
#include <cstddef>

#define IN_F 512
#define C1 64      // H1*F1
#define NH 8
#define FD 8
#define C2 40
#define NEG 0.2f

typedef __attribute__((ext_vector_type(8))) short bf16x8;
typedef __attribute__((ext_vector_type(4))) float f32x4;

__device__ inline unsigned short f32_to_bf16_rne(float f) {
    unsigned int u = __float_as_uint(f);
    unsigned int r = (u + 0x7FFFu + ((u >> 16) & 1u)) >> 16;
    return (unsigned short)r;
}
__device__ inline float bf16_to_f32(unsigned short s) {
    return __uint_as_float(((unsigned int)s) << 16);
}

// ---------------- CSR build ----------------
__global__ __launch_bounds__(256) void hist_k(const int* __restrict__ dst, int* __restrict__ deg,
                                              int* __restrict__ pos, int E) {
    int e = blockIdx.x * 256 + threadIdx.x;
    if (e < E) pos[e] = atomicAdd(&deg[dst[e]], 1);
}

__global__ __launch_bounds__(1024) void scan_local_k(const int* __restrict__ deg, int* __restrict__ rowp,
                                                     int* __restrict__ bsums, int n) {
    __shared__ int tmp[1024];
    int tx = threadIdx.x;
    int i = blockIdx.x * 1024 + tx;
    int v = (i < n) ? deg[i] : 0;
    tmp[tx] = v;
    __syncthreads();
    for (int d = 1; d < 1024; d <<= 1) {
        int t = (tx >= d) ? tmp[tx - d] : 0;
        __syncthreads();
        tmp[tx] += t;
        __syncthreads();
    }
    if (i < n) rowp[i] = tmp[tx] - v;   // exclusive within block
    if (tx == 1023) bsums[blockIdx.x] = tmp[tx];
}

__global__ __launch_bounds__(128) void scan_sums_k(int* bsums, int nb) {
    __shared__ int tmp[128];
    int tx = threadIdx.x;
    int v = (tx < nb) ? bsums[tx] : 0;
    tmp[tx] = v;
    __syncthreads();
    for (int d = 1; d < 128; d <<= 1) {
        int t = (tx >= d) ? tmp[tx - d] : 0;
        __syncthreads();
        tmp[tx] += t;
        __syncthreads();
    }
    if (tx < nb) bsums[tx] = tmp[tx] - v;  // exclusive
}

__global__ __launch_bounds__(1024) void scan_add_k(int* rowp, const int* __restrict__ bsums, int n) {
    int i = blockIdx.x * 1024 + threadIdx.x;
    if (i < n) rowp[i] += bsums[blockIdx.x];
}

__global__ __launch_bounds__(256) void scatter_k(const int* __restrict__ src, const int* __restrict__ dst,
                                                 const int* __restrict__ rowp, const int* __restrict__ pos,
                                                 int* __restrict__ csr_src, int E) {
    int e = blockIdx.x * 256 + threadIdx.x;
    if (e >= E) return;
    csr_src[rowp[dst[e]] + pos[e]] = src[e];
}

// ---------------- W1 preconvert: Wt_hi/Wt_lo[col][k] split-bf16 ----------------
__global__ __launch_bounds__(256) void wt_pre_k(const float* __restrict__ W1,
                                                unsigned short* __restrict__ wt_hi,
                                                unsigned short* __restrict__ wt_lo) {
    int id = blockIdx.x * 256 + threadIdx.x;   // id over 512*64
    if (id >= IN_F * C1) return;
    int col = id & (C1 - 1);
    int k = id >> 6;
    float w = W1[id];
    unsigned short hb = f32_to_bf16_rne(w);
    unsigned short lb = f32_to_bf16_rne(w - bf16_to_f32(hb));
    wt_hi[(size_t)col * IN_F + k] = hb;
    wt_lo[(size_t)col * IN_F + k] = lb;
}

// ---------------- GEMM1 via split-bf16 MFMA; epilogue emits bf16 h rows ----------------
__global__ __launch_bounds__(256) void gemm1_mfma_k(const float* __restrict__ x,
                                                    const unsigned short* __restrict__ wt_hi,
                                                    const unsigned short* __restrict__ wt_lo,
                                                    unsigned short* __restrict__ hb_out, int N) {
    __shared__ alignas(16) unsigned short wlds[2][8192];   // 32 KB
    const int tid = threadIdx.x;
    const int wave = tid >> 6, lane = tid & 63;
    const int m = lane & 15, q = lane >> 4;
    const int row = blockIdx.x * 64 + wave * 16 + m;
    const int row_c = row < N ? row : N - 1;
    const float* xp = x + (size_t)row_c * IN_F + q * 8;

    f32x4 acc[4];
#pragma unroll
    for (int ct = 0; ct < 4; ct++) acc[ct] = (f32x4){0.f, 0.f, 0.f, 0.f};
    float4 xr[2][4];

#define WLOAD(c, buf)                                                                              \
    {                                                                                              \
        _Pragma("unroll") for (int j_ = 0; j_ < 4; j_++) {                                         \
            int slot_ = j_ * 256 + wave * 64 + lane;                                               \
            const unsigned short* gbase_ = (slot_ < 512) ? wt_hi : wt_lo;                          \
            int s_ = slot_ & 511;                                                                  \
            int col_ = s_ & 63, kq_ = s_ >> 6;                                                     \
            const unsigned short* g_ = gbase_ + (size_t)col_ * IN_F + (c) * 64 + kq_ * 8;          \
            unsigned short* l_ = &wlds[buf][0] + (size_t)(j_ * 256 + wave * 64) * 8;               \
            __builtin_amdgcn_global_load_lds((const __attribute__((address_space(1))) unsigned int*)g_, \
                                             (__attribute__((address_space(3))) unsigned int*)l_,  \
                                             16, 0, 0);                                            \
        }                                                                                          \
    }
#define XLOAD(c, r)                                  \
    {                                                \
        const float* xsrc_ = xp + (c) * 64;          \
        (r)[0] = *(const float4*)(xsrc_);            \
        (r)[1] = *(const float4*)(xsrc_ + 4);        \
        (r)[2] = *(const float4*)(xsrc_ + 32);       \
        (r)[3] = *(const float4*)(xsrc_ + 36);       \
    }

    WLOAD(0, 0);
    XLOAD(0, xr[0]);

    for (int c = 0; c < 8; c++) {
        int p = c & 1;
        __syncthreads();
        if (c < 7) {
            WLOAD(c + 1, p ^ 1);
            XLOAD(c + 1, xr[p ^ 1]);
        }
#pragma unroll
        for (int ki = 0; ki < 2; ki++) {
            float f[8];
            f[0] = xr[p][ki * 2].x; f[1] = xr[p][ki * 2].y; f[2] = xr[p][ki * 2].z; f[3] = xr[p][ki * 2].w;
            f[4] = xr[p][ki * 2 + 1].x; f[5] = xr[p][ki * 2 + 1].y; f[6] = xr[p][ki * 2 + 1].z; f[7] = xr[p][ki * 2 + 1].w;
            unsigned int u[8], lu[8];
#pragma unroll
            for (int j = 0; j < 8; j++) u[j] = __float_as_uint(f[j]);
            union { uint4 u4; bf16x8 v; } H, L;
            H.u4.x = __builtin_amdgcn_perm(u[1], u[0], 0x07060302u);
            H.u4.y = __builtin_amdgcn_perm(u[3], u[2], 0x07060302u);
            H.u4.z = __builtin_amdgcn_perm(u[5], u[4], 0x07060302u);
            H.u4.w = __builtin_amdgcn_perm(u[7], u[6], 0x07060302u);
#pragma unroll
            for (int j = 0; j < 8; j++)
                lu[j] = __float_as_uint(f[j] - __uint_as_float(u[j] & 0xFFFF0000u));
            L.u4.x = __builtin_amdgcn_perm(lu[1], lu[0], 0x07060302u);
            L.u4.y = __builtin_amdgcn_perm(lu[3], lu[2], 0x07060302u);
            L.u4.z = __builtin_amdgcn_perm(lu[5], lu[4], 0x07060302u);
            L.u4.w = __builtin_amdgcn_perm(lu[7], lu[6], 0x07060302u);
            int kq = ki * 4 + q;
#pragma unroll
            for (int ct = 0; ct < 4; ct++) {
                int slot = kq * 64 + ct * 16 + m;
                bf16x8 bh = *(const bf16x8*)&wlds[p][slot * 8];
                bf16x8 bl = *(const bf16x8*)&wlds[p][4096 + slot * 8];
                acc[ct] = __builtin_amdgcn_mfma_f32_16x16x32_bf16(H.v, bh, acc[ct], 0, 0, 0);
                acc[ct] = __builtin_amdgcn_mfma_f32_16x16x32_bf16(L.v, bh, acc[ct], 0, 0, 0);
                acc[ct] = __builtin_amdgcn_mfma_f32_16x16x32_bf16(H.v, bl, acc[ct], 0, 0, 0);
            }
        }
    }
    int rbase = blockIdx.x * 64 + wave * 16 + q * 4;
#pragma unroll
    for (int r = 0; r < 4; r++) {
        int ro = rbase + r;
        if (ro < N) {
#pragma unroll
            for (int ct = 0; ct < 4; ct++)
                hb_out[(size_t)ro * C1 + ct * 16 + m] = f32_to_bf16_rne(acc[ct][r]);
        }
    }
#undef WLOAD
#undef XLOAD
}

// ---------------- attn coefs layer1 from bf16 h: el/er[N,8] ----------------
__global__ __launch_bounds__(256) void attn1_k(const unsigned short* __restrict__ hb,
                                               const float* __restrict__ al, const float* __restrict__ ar,
                                               float* __restrict__ el, float* __restrict__ er, int N) {
    int idx = blockIdx.x * 256 + threadIdx.x;
    if (idx >= N * NH) return;
    int n = idx >> 3, hd = idx & 7;
    bf16x8 v = *(const bf16x8*)(hb + (size_t)n * C1 + hd * FD);
    const float4* alp = (const float4*)(al + hd * FD);
    const float4* arp = (const float4*)(ar + hd * FD);
    float4 a0 = alp[0], a1 = alp[1];
    float4 r0 = arp[0], r1 = arp[1];
    float f[8];
#pragma unroll
    for (int j = 0; j < 8; j++) f[j] = bf16_to_f32((unsigned short)v[j]);
    float e_l = f[0] * a0.x + f[1] * a0.y + f[2] * a0.z + f[3] * a0.w +
                f[4] * a1.x + f[5] * a1.y + f[6] * a1.z + f[7] * a1.w;
    float e_r = f[0] * r0.x + f[1] * r0.y + f[2] * r0.z + f[3] * r0.w +
                f[4] * r1.x + f[5] * r1.y + f[6] * r1.z + f[7] * r1.w;
    el[idx] = e_l;
    er[idx] = e_r;
}

// ---------------- layer1: one wave per node, bf16 h gather (2 lines/edge) ----------------
__global__ __launch_bounds__(256) void l1_wave_k(const unsigned short* __restrict__ hb,
                                                 const float* __restrict__ el, const float* __restrict__ er,
                                                 const int* __restrict__ rowp, const int* __restrict__ deg,
                                                 const int* __restrict__ csr_src, const float* __restrict__ b1,
                                                 float* __restrict__ h1out, int N) {
    int n = (blockIdx.x * 256 + threadIdx.x) >> 6;   // node = global wave id
    if (n >= N) return;
    int lane = threadIdx.x & 63;
    int hg = lane >> 3;                              // head
    int start = rowp[n], cnt = deg[n];
    float erd = er[n * NH + hg];
    float acc = 0.f, s = 0.f;
    int i = 0;
    for (; i + 4 <= cnt; i += 4) {
        const int* cp = csr_src + start + i;
        int sn0 = cp[0], sn1 = cp[1], sn2 = cp[2], sn3 = cp[3];
        float e0 = el[sn0 * NH + hg];
        float e1 = el[sn1 * NH + hg];
        float e2 = el[sn2 * NH + hg];
        float e3 = el[sn3 * NH + hg];
        unsigned short q0 = hb[(size_t)sn0 * C1 + lane];
        unsigned short q1 = hb[(size_t)sn1 * C1 + lane];
        unsigned short q2 = hb[(size_t)sn2 * C1 + lane];
        unsigned short q3 = hb[(size_t)sn3 * C1 + lane];
        e0 += erd; e1 += erd; e2 += erd; e3 += erd;
        e0 = e0 > 0.f ? e0 : NEG * e0;
        e1 = e1 > 0.f ? e1 : NEG * e1;
        e2 = e2 > 0.f ? e2 : NEG * e2;
        e3 = e3 > 0.f ? e3 : NEG * e3;
        float w0 = __expf(e0), w1 = __expf(e1), w2 = __expf(e2), w3 = __expf(e3);
        s += (w0 + w1) + (w2 + w3);
        acc += w0 * bf16_to_f32(q0) + w1 * bf16_to_f32(q1) + w2 * bf16_to_f32(q2) + w3 * bf16_to_f32(q3);
    }
    for (; i < cnt; i++) {
        int sn = csr_src[start + i];
        float e = el[sn * NH + hg] + erd;
        e = e > 0.f ? e : NEG * e;
        float w0 = __expf(e);
        s += w0;
        acc += w0 * bf16_to_f32(hb[(size_t)sn * C1 + lane]);
    }
    float sinv = (s > 0.f) ? 1.f / s : 0.f;
    float o = acc * sinv + b1[lane];
    o = o > 0.f ? o : (__expf(o) - 1.f);   // elu
    h1out[(size_t)n * C1 + lane] = o;
}

// ---------------- GEMM2 + attn2: h2b[N,64] bf16 (40 real + 24 pad), el2/er2 fp32 ----------------
__global__ __launch_bounds__(256) void gemm2_attn2_k(const float* __restrict__ h1, const float* __restrict__ W2,
                                                     const float* __restrict__ al2, const float* __restrict__ ar2,
                                                     unsigned short* __restrict__ h2b, float* __restrict__ el2,
                                                     float* __restrict__ er2, int N) {
    __shared__ float ws[C1 * C2];   // 10 KB
    __shared__ float hs[64][C1];    // 16 KB
    __shared__ float h2s[64][C2];   // 10 KB
    __shared__ float a2s[2 * C2];
    int t = threadIdx.x;
    int n0 = blockIdx.x * 64;
    for (int i = t; i < C1 * C2; i += 256) ws[i] = W2[i];
    if (t < C2) a2s[t] = al2[t];
    else if (t < 2 * C2) a2s[t] = ar2[t - C2];
    for (int i = t; i < 64 * 16; i += 256) {
        int r = i >> 4, c4 = i & 15;
        int n = n0 + r;
        float4 v = (n < N) ? *(const float4*)(h1 + (size_t)n * C1 + c4 * 4) : make_float4(0.f, 0.f, 0.f, 0.f);
        *(float4*)&hs[r][c4 * 4] = v;
    }
    __syncthreads();
    for (int o = t; o < 64 * C2; o += 256) {
        int r = o / C2, c = o % C2;
        float sum = 0.f;
#pragma unroll
        for (int k = 0; k < C1; k++) sum += hs[r][k] * ws[k * C2 + c];
        h2s[r][c] = sum;
    }
    __syncthreads();
    // write padded bf16 rows
    for (int o = t; o < 64 * 64; o += 256) {
        int r = o >> 6, c = o & 63;
        int nn = n0 + r;
        if (nn < N) h2b[(size_t)nn * 64 + c] = (c < C2) ? f32_to_bf16_rne(h2s[r][c]) : (unsigned short)0;
    }
    if (t < 64) {
        int nn = n0 + t;
        if (nn < N) {
            float e_l = 0.f, e_r = 0.f;
#pragma unroll
            for (int c = 0; c < C2; c++) {
                float v = h2s[t][c];
                e_l += v * a2s[c];
                e_r += v * a2s[C2 + c];
            }
            el2[nn] = e_l;
            er2[nn] = e_r;
        }
    }
}

// ---------------- layer2: 8 lanes/node, bf16 padded-row gather (2 lines/edge) ----------------
__global__ __launch_bounds__(256) void l2_fused_k(const unsigned short* __restrict__ h2b,
                                                  const float* __restrict__ el, const float* __restrict__ er,
                                                  const int* __restrict__ rowp, const int* __restrict__ deg,
                                                  const int* __restrict__ csr_src, const float* __restrict__ b2,
                                                  float* __restrict__ out, int N) {
    int tid = threadIdx.x;
    int n = blockIdx.x * 32 + (tid >> 3);
    int sub = tid & 7;
    if (n >= N) return;
    int start = rowp[n], cnt = deg[n];
    float erd = er[n];
    float s = 0.f;
    float acc[8];
#pragma unroll
    for (int j = 0; j < 8; j++) acc[j] = 0.f;
    int i = 0;
    for (; i + 4 <= cnt; i += 4) {
        const int* cp = csr_src + start + i;
        int sn0 = cp[0], sn1 = cp[1], sn2 = cp[2], sn3 = cp[3];
        float e0 = el[sn0], e1 = el[sn1], e2 = el[sn2], e3 = el[sn3];
        bf16x8 v0 = *(const bf16x8*)(h2b + (size_t)sn0 * 64 + sub * 8);
        bf16x8 v1 = *(const bf16x8*)(h2b + (size_t)sn1 * 64 + sub * 8);
        bf16x8 v2 = *(const bf16x8*)(h2b + (size_t)sn2 * 64 + sub * 8);
        bf16x8 v3 = *(const bf16x8*)(h2b + (size_t)sn3 * 64 + sub * 8);
        e0 += erd; e1 += erd; e2 += erd; e3 += erd;
        e0 = e0 > 0.f ? e0 : NEG * e0;
        e1 = e1 > 0.f ? e1 : NEG * e1;
        e2 = e2 > 0.f ? e2 : NEG * e2;
        e3 = e3 > 0.f ? e3 : NEG * e3;
        float w0 = __expf(e0), w1 = __expf(e1), w2 = __expf(e2), w3 = __expf(e3);
        s += (w0 + w1) + (w2 + w3);
#pragma unroll
        for (int j = 0; j < 8; j++) {
            acc[j] += w0 * bf16_to_f32((unsigned short)v0[j]) + w1 * bf16_to_f32((unsigned short)v1[j]) +
                      w2 * bf16_to_f32((unsigned short)v2[j]) + w3 * bf16_to_f32((unsigned short)v3[j]);
        }
    }
    for (; i < cnt; i++) {
        int sn = csr_src[start + i];
        float e = el[sn] + erd;
        e = e > 0.f ? e : NEG * e;
        float w0 = __expf(e);
        s += w0;
        bf16x8 v = *(const bf16x8*)(h2b + (size_t)sn * 64 + sub * 8);
#pragma unroll
        for (int j = 0; j < 8; j++) acc[j] += w0 * bf16_to_f32((unsigned short)v[j]);
    }
    float sinv = (s > 0.f) ? 1.f / s : 0.f;
    float vals[8];
#pragma unroll
    for (int j = 0; j < 8; j++) {
        int c = sub * 8 + j;
        vals[j] = (c < C2) ? (acc[j] * sinv + b2[c]) : -1e30f;
    }
    float mx = vals[0];
#pragma unroll
    for (int j = 1; j < 8; j++) mx = fmaxf(mx, vals[j]);
#pragma unroll
    for (int off = 1; off < 8; off <<= 1) mx = fmaxf(mx, __shfl_xor(mx, off, 8));
    float se = 0.f;
#pragma unroll
    for (int j = 0; j < 8; j++) se += __expf(vals[j] - mx);
#pragma unroll
    for (int off = 1; off < 8; off <<= 1) se += __shfl_xor(se, off, 8);
    float ls = __logf(se) + mx;
    if (sub < 5) {
        float* op = out + (size_t)n * C2 + sub * 8;
        *(float4*)(op) = make_float4(vals[0] - ls, vals[1] - ls, vals[2] - ls, vals[3] - ls);
        *(float4*)(op + 4) = make_float4(vals[4] - ls, vals[5] - ls, vals[6] - ls, vals[7] - ls);
    }
}

extern "C" void kernel_launch(void* const* d_in, const int* in_sizes, int n_in,
                              void* d_out, int out_size, void* d_ws, size_t ws_size,
                              hipStream_t stream) {
    (void)n_in; (void)out_size; (void)ws_size;
    const float* x   = (const float*)d_in[0];
    const int*   src = (const int*)d_in[1];
    const int*   dst = (const int*)d_in[2];
    const float* W1  = (const float*)d_in[3];
    const float* al1 = (const float*)d_in[4];
    const float* ar1 = (const float*)d_in[5];
    const float* b1  = (const float*)d_in[6];
    const float* W2  = (const float*)d_in[7];
    const float* al2 = (const float*)d_in[8];
    const float* ar2 = (const float*)d_in[9];
    const float* b2  = (const float*)d_in[10];
    float* out = (float*)d_out;
    const int N = in_sizes[0] / IN_F;
    const int E = in_sizes[1];

    char* w = (char*)d_ws;
    auto alloc = [&](size_t bytes) -> char* {
        char* p = w;
        w += (bytes + 255) & ~(size_t)255;
        return p;
    };
    int* deg     = (int*)alloc((size_t)N * 4);
    int* rowp    = (int*)alloc((size_t)N * 4);
    int* bsums   = (int*)alloc(512);
    int* pos     = (int*)alloc((size_t)E * 4);
    int* csr_src = (int*)alloc((size_t)E * 4);
    unsigned short* wt_hi = (unsigned short*)alloc((size_t)IN_F * C1 * 2);
    unsigned short* wt_lo = (unsigned short*)alloc((size_t)IN_F * C1 * 2);
    unsigned short* hb    = (unsigned short*)alloc((size_t)N * C1 * 2);
    float* el1   = (float*)alloc((size_t)N * NH * 4);
    float* er1   = (float*)alloc((size_t)N * NH * 4);
    float* h1    = (float*)alloc((size_t)N * C1 * 4);
    unsigned short* h2b = (unsigned short*)alloc((size_t)N * 64 * 2);
    float* el2   = (float*)alloc((size_t)N * 4);
    float* er2   = (float*)alloc((size_t)N * 4);

    hipMemsetAsync(deg, 0, (size_t)N * 4, stream);

    int ebl = (E + 255) / 256;
    int nb = (N + 1023) / 1024;
    hist_k<<<ebl, 256, 0, stream>>>(dst, deg, pos, E);
    scan_local_k<<<nb, 1024, 0, stream>>>(deg, rowp, bsums, N);
    scan_sums_k<<<1, 128, 0, stream>>>(bsums, nb);
    scan_add_k<<<nb, 1024, 0, stream>>>(rowp, bsums, N);
    scatter_k<<<ebl, 256, 0, stream>>>(src, dst, rowp, pos, csr_src, E);

    wt_pre_k<<<(IN_F * C1 + 255) / 256, 256, 0, stream>>>(W1, wt_hi, wt_lo);
    gemm1_mfma_k<<<(N + 63) / 64, 256, 0, stream>>>(x, wt_hi, wt_lo, hb, N);
    attn1_k<<<(N * NH + 255) / 256, 256, 0, stream>>>(hb, al1, ar1, el1, er1, N);
    l1_wave_k<<<(N * 64 + 255) / 256, 256, 0, stream>>>(hb, el1, er1, rowp, deg, csr_src, b1, h1, N);
    gemm2_attn2_k<<<(N + 63) / 64, 256, 0, stream>>>(h1, W2, al2, ar2, h2b, el2, er2, N);
    l2_fused_k<<<(N + 31) / 32, 256, 0, stream>>>(h2b, el2, er2, rowp, deg, csr_src, b2, out, N);
}